// Round 3
// baseline (23551.195 us; speedup 1.0000x reference)
//
#include <hip/hip_runtime.h>
#include <hip/hip_bf16.h>

typedef __hip_bfloat16 bf16;

#define B_      64
#define NMAX_   299
#define N_      300
#define D_      512
#define H_      512
#define NHEADS_ 8
#define NHID_   64
#define SCLD    304                  // padded leading dim for (n,m) score rows
#define SCSZ    (N_ * SCLD)          // 91,200 floats per batch

// ---------------------------------------------------------------- utilities

__device__ __forceinline__ float sigmoidf_(float x) { return 1.0f / (1.0f + expf(-x)); }

// Monotone-counter grid barrier. Release/acquire at agent scope so per-XCD
// L2s write back / invalidate around the counter (G16).
__device__ __forceinline__ void gridbar(unsigned* bar, unsigned target) {
    __syncthreads();
    if (threadIdx.x == 0) {
        __threadfence();  // release: drain + wb this XCD's L2
        __hip_atomic_fetch_add(bar, 1u, __ATOMIC_ACQ_REL, __HIP_MEMORY_SCOPE_AGENT);
        while (__hip_atomic_load(bar, __ATOMIC_ACQUIRE, __HIP_MEMORY_SCOPE_AGENT) < target) {
            __builtin_amdgcn_s_sleep(2);
        }
        __threadfence();  // acquire: invalidate stale lines before re-reading hbuf
    }
    __syncthreads();
}

// ---------------------------------------------------------------- embedding

__global__ void embed_k(const int* __restrict__ tokens, const int* __restrict__ tok_lens,
                        const int* __restrict__ seq_lens, const float* __restrict__ emb,
                        float* __restrict__ out)
{
    const int n = blockIdx.x, b = blockIdx.y;
    const int d = threadIdx.x * 4;
    const int nc = seq_lens[b] - 1;
    float4 v;
    if (n < nc) {
        const int tl = tok_lens[b * NMAX_ + n];
        const int* tp = tokens + (b * NMAX_ + n) * 8;
        float4 acc = {0.f, 0.f, 0.f, 0.f};
        for (int t = 0; t < 8; ++t) {
            if (t < tl) {
                const float4 e = *(const float4*)(emb + (long)tp[t] * D_ + d);
                acc.x += e.x; acc.y += e.y; acc.z += e.z; acc.w += e.w;
            }
        }
        const float inv = 1.0f / (float)nc;
        v.x = acc.x * inv; v.y = acc.y * inv; v.z = acc.z * inv; v.w = acc.w * inv;
    } else {
        const int row = (n == nc) ? 2 : 0;
        v = *(const float4*)(emb + row * D_ + d);
    }
    *(float4*)(out + ((long)b * N_ + n) * D_ + d) = v;
}

// ------------------------------------------------------------------- cond

__global__ void cond_k(const float* __restrict__ adj, unsigned char* __restrict__ cond)
{
    __shared__ float T1[64][65];
    __shared__ float T2[64][65];
    const int b = blockIdx.z;
    const int n0 = blockIdx.x * 64, m0 = blockIdx.y * 64;
    const int jj = threadIdx.x & 63, i0 = threadIdx.x >> 6;
    for (int r = 0; r < 16; ++r) {
        const int i = i0 * 16 + r;
        const int n = n0 + i, m = m0 + jj;
        T1[i][jj] = (n < N_ && m < N_) ? adj[((long)b * N_ + n) * N_ + m] : 0.f;
        const int n2 = m0 + i, m2 = n0 + jj;
        T2[i][jj] = (n2 < N_ && m2 < N_) ? adj[((long)b * N_ + n2) * N_ + m2] : 0.f;
    }
    __syncthreads();
    for (int r = 0; r < 16; ++r) {
        const int i = i0 * 16 + r;
        const int n = n0 + i, m = m0 + jj;
        if (n < N_ && m < N_) {
            const float v = T1[i][jj] + T2[jj][i] + ((n == m) ? 1.f : 0.f);
            cond[((long)b * N_ + n) * N_ + m] = (v > 0.f) ? 1 : 0;
        }
    }
}

// ------------------------------------------------------- generic fp32 GEMM
// C[m][n] = sum_k A[m][k] * (BT ? B[n][k] : B[k][n]) ; batched over blockIdx.z

template<bool BT, bool OBF>
__global__ __launch_bounds__(256) void gemm_k(
    const float* __restrict__ A, long sA, int lda,
    const float* __restrict__ B, long sB, int ldb,
    void* __restrict__ C, long sC, int ldc,
    int M, int N, int K)
{
    __shared__ alignas(16) float As[16][64];
    __shared__ alignas(16) float Bs[16][64];
    const int z = blockIdx.z;
    const float* Ab = A + (long)z * sA;
    const float* Bb = B + (long)z * sB;
    const int m0 = blockIdx.x * 64, n0 = blockIdx.y * 64;
    const int tid = threadIdx.x;
    const int tx = tid & 15, ty = tid >> 4;
    const int amm = tid >> 2, ak4 = (tid & 3) * 4;
    float acc[4][4] = {};

    for (int k0 = 0; k0 < K; k0 += 16) {
        // stage A (rows m, contiguous k)
        {
            float4 v = {0.f, 0.f, 0.f, 0.f};
            const int row = m0 + amm;
            if (row < M) {
                if (k0 + ak4 + 3 < K) {
                    v = *(const float4*)(Ab + (long)row * lda + k0 + ak4);
                } else {
                    float* vp = (float*)&v;
                    for (int j = 0; j < 4; ++j)
                        if (k0 + ak4 + j < K) vp[j] = Ab[(long)row * lda + k0 + ak4 + j];
                }
            }
            As[ak4 + 0][amm] = v.x; As[ak4 + 1][amm] = v.y;
            As[ak4 + 2][amm] = v.z; As[ak4 + 3][amm] = v.w;
        }
        // stage B
        if (BT) {
            float4 v = {0.f, 0.f, 0.f, 0.f};
            const int row = n0 + amm;
            if (row < N) {
                if (k0 + ak4 + 3 < K) {
                    v = *(const float4*)(Bb + (long)row * ldb + k0 + ak4);
                } else {
                    float* vp = (float*)&v;
                    for (int j = 0; j < 4; ++j)
                        if (k0 + ak4 + j < K) vp[j] = Bb[(long)row * ldb + k0 + ak4 + j];
                }
            }
            Bs[ak4 + 0][amm] = v.x; Bs[ak4 + 1][amm] = v.y;
            Bs[ak4 + 2][amm] = v.z; Bs[ak4 + 3][amm] = v.w;
        } else {
            const int nn = tid & 63, kb = tid >> 6;
            #pragma unroll
            for (int r = 0; r < 4; ++r) {
                const int kk = kb * 4 + r;
                float v = 0.f;
                if (k0 + kk < K && n0 + nn < N) v = Bb[(long)(k0 + kk) * ldb + n0 + nn];
                Bs[kk][nn] = v;
            }
        }
        __syncthreads();
        #pragma unroll
        for (int kk = 0; kk < 16; ++kk) {
            const float4 av = *(const float4*)&As[kk][ty * 4];
            const float4 bv = *(const float4*)&Bs[kk][tx * 4];
            const float* ap = (const float*)&av;
            const float* bp = (const float*)&bv;
            #pragma unroll
            for (int i = 0; i < 4; ++i)
                #pragma unroll
                for (int j = 0; j < 4; ++j)
                    acc[i][j] = fmaf(ap[i], bp[j], acc[i][j]);
        }
        __syncthreads();
    }
    for (int i = 0; i < 4; ++i) {
        const int m = m0 + ty * 4 + i;
        if (m >= M) break;
        for (int j = 0; j < 4; ++j) {
            const int nn = n0 + tx * 4 + j;
            if (nn < N) {
                const long idx = (long)z * sC + (long)m * ldc + nn;
                if (OBF) ((bf16*)C)[idx] = __float2bfloat16(acc[i][j]);
                else     ((float*)C)[idx] = acc[i][j];
            }
        }
    }
}

// ------------------------------------------------- softmaxes for GAT layer

// softmax over batch axis: per padded (n,m) slot compute max_b, sum_b exp.
// Pad columns (m>=300) hold poison but are finite and never consumed.
__global__ void bsoft_k(const float* __restrict__ sc, float* __restrict__ mx, float* __restrict__ sm)
{
    const int idx = blockIdx.x * 256 + threadIdx.x;
    if (idx >= SCSZ) return;
    float m = -1e30f;
    for (int b = 0; b < B_; ++b) m = fmaxf(m, sc[(long)b * SCSZ + idx]);
    float s = 0.f;
    for (int b = 0; b < B_; ++b) s += expf(sc[(long)b * SCSZ + idx] - m);
    mx[idx] = m; sm[idx] = s;
}

// masked softmax over n (per (b,m) column); in-place overwrite of sc with att2
__global__ void colsoft_k(float* __restrict__ sc, const float* __restrict__ mx,
                          const float* __restrict__ sm, const unsigned char* __restrict__ cond)
{
    const int m = blockIdx.x * 256 + threadIdx.x;
    const int b = blockIdx.y;
    if (m >= N_) return;
    float* scb = sc + (long)b * SCSZ;
    const unsigned char* cb = cond + (long)b * (N_ * N_);
    float vmax = -1e30f;
    for (int n = 0; n < N_; ++n) {
        const int o = n * SCLD + m;
        if (cb[n * N_ + m]) {
            const float e = expf(scb[o] - mx[o]) / sm[o];
            vmax = fmaxf(vmax, e);
        }
    }
    float ssum = 0.f;
    for (int n = 0; n < N_; ++n) {
        const int o = n * SCLD + m;
        if (cb[n * N_ + m]) ssum += expf(expf(scb[o] - mx[o]) / sm[o] - vmax);
    }
    const float inv = 1.0f / ssum;
    for (int n = 0; n < N_; ++n) {
        const int o = n * SCLD + m;
        float v = 0.f;
        if (cb[n * N_ + m]) v = expf(expf(scb[o] - mx[o]) / sm[o] - vmax) * inv;
        scb[o] = v;
    }
}

// softmax over n per (b,f) column of hp (B,N,512); ELU after layer2 is identity
// on softmax outputs (all >= 0), so this kernel serves both layers.
__global__ void nsoft_k(const float* __restrict__ hp, float* __restrict__ out)
{
    const int f = blockIdx.x * 256 + threadIdx.x;  // 0..511
    const int b = blockIdx.y;
    const float* hb = hp + (long)b * (N_ * 512) + f;
    float vmax = -1e30f;
    for (int n = 0; n < N_; ++n) vmax = fmaxf(vmax, hb[n * 512]);
    float s = 0.f;
    for (int n = 0; n < N_; ++n) s += expf(hb[n * 512] - vmax);
    const float inv = 1.0f / s;
    float* ob = out + (long)b * (N_ * 512) + f;
    for (int n = 0; n < N_; ++n) ob[n * 512] = expf(hb[n * 512] - vmax) * inv;
}

// ----------------------------------------------------------------- GRU prep

__global__ void xrev_k(const float* __restrict__ out2, const int* __restrict__ seq_lens,
                       float* __restrict__ xr)
{
    const int t = blockIdx.x, b = blockIdx.y;
    const int d = threadIdx.x * 4;
    int src = seq_lens[b] - 1 - t;
    if (src < 0) src = 0;
    *(float4*)(xr + ((long)t * B_ + b) * 512 + d) =
        *(const float4*)(out2 + ((long)b * N_ + src) * 512 + d);
}

__global__ void zero_k(float* __restrict__ p, long n)
{
    for (long i = (long)blockIdx.x * 256 + threadIdx.x; i < n; i += (long)gridDim.x * 256)
        p[i] = 0.f;
}

// ------------------------------------------------------ GRU recurrence
// 256 blocks x 256 threads, persistent; block = (dir, 4 hidden units) x 64 batches.
// h double-buffered in global (layout [phase][dir][k][b]); staged via LDS in
// 128-k quarters. Weights are wave-uniform (readfirstlane on ug) -> s_loads.

__global__ __launch_bounds__(256) void gru_recur(
    const bf16* __restrict__ gif, const bf16* __restrict__ gib,
    const float* __restrict__ Whh, const float* __restrict__ bih,
    const float* __restrict__ bhh, const int* __restrict__ seq_lens,
    float* __restrict__ hbuf, unsigned* __restrict__ bar,
    float* __restrict__ outacc)
{
    __shared__ alignas(16) float hs[128 * 64];  // 32 KB
    const int tid = threadIdx.x;
    const int b = tid & 63;
    const int ug = __builtin_amdgcn_readfirstlane(tid >> 6);
    const int dir = blockIdx.x >> 7;
    const int u = (blockIdx.x & 127) * 4 + ug;

    const float* W = Whh + (long)dir * (1536 * 512) + (long)u * 512;
    const bf16* gi = dir ? gib : gif;
    const float cr = bih[dir * 1536 + u];
    const float cz = bih[dir * 1536 + 512 + u];
    const float cn = bih[dir * 1536 + 1024 + u];
    const float br = bhh[dir * 1536 + u];
    const float bz = bhh[dir * 1536 + 512 + u];
    const float bn = bhh[dir * 1536 + 1024 + u];
    const int sl = seq_lens[b];

    // zero phase-0 slice
    hbuf[dir * 32768 + u * 64 + b] = 0.0f;
    unsigned target = 256;
    gridbar(bar, target);

    for (int t = 0; t < N_; ++t) {
        const float* hc = hbuf + ((t & 1) ? 65536 : 0) + dir * 32768;
        float* hn       = hbuf + ((t & 1) ? 0 : 65536) + dir * 32768;
        float ar = 0.f, az = 0.f, an = 0.f, hprev = 0.f;
        for (int q = 0; q < 4; ++q) {
            __syncthreads();
            const float4* src = (const float4*)(hc + q * 8192);
            float4* dst = (float4*)hs;
            #pragma unroll
            for (int i = 0; i < 8; ++i) dst[tid + 256 * i] = src[tid + 256 * i];
            __syncthreads();
            const float* wr = W + q * 128;
            const float* wz = wr + 262144;
            const float* wn = wr + 524288;
            #pragma unroll 8
            for (int k = 0; k < 128; ++k) {
                const float hk = hs[k * 64 + b];
                ar = fmaf(hk, wr[k], ar);
                az = fmaf(hk, wz[k], az);
                an = fmaf(hk, wn[k], an);
            }
            if (q == (u >> 7)) hprev = hs[(u & 127) * 64 + b];
        }
        const long gbase = (long)t * 98304 + (long)u * 64 + b;
        const float gr = cr + __bfloat162float(gi[gbase]);
        const float gz = cz + __bfloat162float(gi[gbase + 32768]);
        const float gn = cn + __bfloat162float(gi[gbase + 65536]);
        const float r  = sigmoidf_(gr + br + ar);
        const float zg = sigmoidf_(gz + bz + az);
        const float nn = tanhf(gn + r * (bn + an));
        const float hnew = (1.f - zg) * nn + zg * hprev;
        const bool msk = t < sl;
        hn[u * 64 + b] = msk ? hnew : hprev;
        if (msk) {
            const int slot = dir ? (sl - 1 - t) : t;
            atomicAdd(&outacc[((long)slot * B_ + b) * 512 + u], hnew);
        }
        target += 256;
        gridbar(bar, target);
    }
}

// --------------------------------------------------------------- finalize
// Reference outputs are float32 -> d_out is float*. (Rounds 1-2 wrote bf16
// here; the harness read fp32 words built from bf16 pairs -> absmax ~2x max.)

__global__ void final_k(const float* __restrict__ outacc, const float* __restrict__ hbuf,
                        float* __restrict__ dout)
{
    const long i = (long)blockIdx.x * 256 + threadIdx.x;
    const long NOUT = (long)N_ * B_ * 512;  // 9,830,400
    if (i < NOUT) {
        dout[i] = outacc[i];
    } else if (i < NOUT + 2 * B_ * 512) {
        const long j = i - NOUT;
        const int dir = (int)(j >> 15);
        const int b = (int)((j >> 9) & 63);
        const int u = (int)(j & 511);
        dout[i] = hbuf[dir * 32768 + u * 64 + b];  // phase 0 holds final h
    }
}

__global__ void fail_zero_k(float* __restrict__ dout, long n)
{
    for (long i = (long)blockIdx.x * 256 + threadIdx.x; i < n; i += (long)gridDim.x * 256)
        dout[i] = 0.f;
}

// ----------------------------------------------------------------- launch

extern "C" void kernel_launch(void* const* d_in, const int* in_sizes, int n_in,
                              void* d_out, int out_size, void* d_ws, size_t ws_size,
                              hipStream_t stream)
{
    const int*   tokens   = (const int*)d_in[0];
    const int*   tok_lens = (const int*)d_in[1];
    const int*   seq_lens = (const int*)d_in[2];
    const float* adj      = (const float*)d_in[3];
    const float* emb      = (const float*)d_in[4];
    const float* Wq       = (const float*)d_in[5];
    const float* Wk       = (const float*)d_in[6];
    const float* Wq_o     = (const float*)d_in[7];
    const float* Wk_o     = (const float*)d_in[8];
    const float* gWih     = (const float*)d_in[9];
    const float* gWhh     = (const float*)d_in[10];
    const float* gbih     = (const float*)d_in[11];
    const float* gbhh     = (const float*)d_in[12];
    float* out = (float*)d_out;

    const long SZ = (long)B_ * N_ * 512;  // 9,830,400 floats
    float* bufA = (float*)d_ws;            // embedded -> q2 -> out_accum
    float* bufB = bufA + SZ;               // q1 -> k2
    float* bufC = bufB + SZ;               // k1 -> out2
    float* bufD = bufC + SZ;               // x1 -> x_rev
    float* bufE = bufD + SZ;               // hp (both layers)
    float* sc   = bufE + SZ;               // (B, N, SCLD) scores/att
    float* mx   = sc + (long)B_ * SCSZ;
    float* smv  = mx + SCSZ;
    unsigned char* cond = (unsigned char*)(smv + SCSZ);          // B*N*N bytes (dense)
    bf16* gif = (bf16*)(cond + (long)B_ * N_ * N_);              // (300,1536,64) bf16
    bf16* gib = gif + (long)N_ * 1536 * B_;
    float* hbuf = (float*)(gib + (long)N_ * 1536 * B_);          // 2 phases x 2 dirs x 512 x 64
    unsigned* bar = (unsigned*)(hbuf + 131072);
    const size_t needed = (size_t)((char*)(bar + 64) - (char*)d_ws);
    if (ws_size < needed) {  // fail visibly, not via OOB
        fail_zero_k<<<4096, 256, 0, stream>>>(out, out_size);
        return;
    }

    // 1. embedding + cond mask
    embed_k<<<dim3(N_, B_), 128, 0, stream>>>(tokens, tok_lens, seq_lens, emb, bufA);
    cond_k<<<dim3(5, 5, B_), 256, 0, stream>>>(adj, cond);

    // 2. layer-1 projections (batched over 8 heads): q1 -> bufB, k1 -> bufC
    gemm_k<false, false><<<dim3(300, 1, 8), 256, 0, stream>>>(
        bufA, 0, 512, Wq, 32768, 64, bufB, 64, 512, B_ * N_, 64, 512);
    gemm_k<false, false><<<dim3(300, 1, 8), 256, 0, stream>>>(
        bufA, 0, 512, Wk, 32768, 64, bufC, 64, 512, B_ * N_, 64, 512);

    // 3. per-head attention
    for (int h = 0; h < NHEADS_; ++h) {
        gemm_k<true, false><<<dim3(5, 5, B_), 256, 0, stream>>>(         // scores = q k^T
            bufB + h * 64, (long)N_ * 512, 512,
            bufC + h * 64, (long)N_ * 512, 512,
            sc, SCSZ, SCLD, N_, N_, 64);
        bsoft_k<<<(SCSZ + 255) / 256, 256, 0, stream>>>(sc, mx, smv);
        colsoft_k<<<dim3(2, B_), 256, 0, stream>>>(sc, mx, smv, cond);
        gemm_k<false, false><<<dim3(5, 1, B_), 256, 0, stream>>>(        // hp = att2 @ k
            sc, SCSZ, SCLD,
            bufC + h * 64, (long)N_ * 512, 512,
            bufE + h * 64, (long)N_ * 512, 512, N_, 64, N_);
    }
    nsoft_k<<<dim3(2, B_), 256, 0, stream>>>(bufE, bufD);                // x1 -> bufD

    // 4. layer-2: q2 -> bufA, k2 -> bufB
    gemm_k<false, false><<<dim3(300, 8, 1), 256, 0, stream>>>(
        bufD, 0, 512, Wq_o, 0, 512, bufA, 0, 512, B_ * N_, 512, 512);
    gemm_k<false, false><<<dim3(300, 8, 1), 256, 0, stream>>>(
        bufD, 0, 512, Wk_o, 0, 512, bufB, 0, 512, B_ * N_, 512, 512);
    gemm_k<true, false><<<dim3(5, 5, B_), 256, 0, stream>>>(
        bufA, (long)N_ * 512, 512, bufB, (long)N_ * 512, 512,
        sc, SCSZ, SCLD, N_, N_, 512);
    bsoft_k<<<(SCSZ + 255) / 256, 256, 0, stream>>>(sc, mx, smv);
    colsoft_k<<<dim3(2, B_), 256, 0, stream>>>(sc, mx, smv, cond);
    gemm_k<false, false><<<dim3(5, 8, B_), 256, 0, stream>>>(            // hp2 = att2 @ k2
        sc, SCSZ, SCLD, bufB, (long)N_ * 512, 512,
        bufE, (long)N_ * 512, 512, N_, 512, N_);
    nsoft_k<<<dim3(2, B_), 256, 0, stream>>>(bufE, bufC);                // out2 -> bufC (elu = id)

    // 5. GRU input GEMMs (bf16 out, layout (t, j, b))
    xrev_k<<<dim3(N_, B_), 128, 0, stream>>>(bufC, seq_lens, bufD);
    zero_k<<<2048, 256, 0, stream>>>(bufA, SZ);                          // out_accum
    zero_k<<<1, 256, 0, stream>>>((float*)bar, 64);
    gemm_k<true, true><<<dim3(24, 1, N_), 256, 0, stream>>>(             // gi_f
        gWih, 0, 512, bufC, 512, (long)N_ * 512, gif, 1536 * 64, 64, 1536, 64, 512);
    gemm_k<true, true><<<dim3(24, 1, N_), 256, 0, stream>>>(             // gi_b
        gWih + 1536 * 512, 0, 512, bufD, (long)B_ * 512, 512, gib, 1536 * 64, 64, 1536, 64, 512);

    // 6. recurrence (persistent, grid-synced) + finalize to fp32
    gru_recur<<<256, 256, 0, stream>>>(gif, gib, gWhh, gbih, gbhh, seq_lens, hbuf, bar, bufA);
    final_k<<<38656, 256, 0, stream>>>(bufA, hbuf, out);
}

// Round 4
// 15000.146 us; speedup vs baseline: 1.5701x; 1.5701x over previous
//
#include <hip/hip_runtime.h>
#include <hip/hip_bf16.h>

typedef __hip_bfloat16 bf16;

#define B_      64
#define NMAX_   299
#define N_      300
#define D_      512
#define H_      512
#define NHEADS_ 8
#define NHID_   64
#define SCLD    304                  // padded leading dim for (n,m) score rows
#define SCSZ    (N_ * SCLD)          // 91,200 floats per batch

// ---------------------------------------------------------------- utilities

__device__ __forceinline__ float sigmoidf_(float x) { return 1.0f / (1.0f + expf(-x)); }

// ---------------------------------------------------------------- embedding

__global__ void embed_k(const int* __restrict__ tokens, const int* __restrict__ tok_lens,
                        const int* __restrict__ seq_lens, const float* __restrict__ emb,
                        float* __restrict__ out)
{
    const int n = blockIdx.x, b = blockIdx.y;
    const int d = threadIdx.x * 4;
    const int nc = seq_lens[b] - 1;
    float4 v;
    if (n < nc) {
        const int tl = tok_lens[b * NMAX_ + n];
        const int* tp = tokens + (b * NMAX_ + n) * 8;
        float4 acc = {0.f, 0.f, 0.f, 0.f};
        for (int t = 0; t < 8; ++t) {
            if (t < tl) {
                const float4 e = *(const float4*)(emb + (long)tp[t] * D_ + d);
                acc.x += e.x; acc.y += e.y; acc.z += e.z; acc.w += e.w;
            }
        }
        const float inv = 1.0f / (float)nc;
        v.x = acc.x * inv; v.y = acc.y * inv; v.z = acc.z * inv; v.w = acc.w * inv;
    } else {
        const int row = (n == nc) ? 2 : 0;
        v = *(const float4*)(emb + row * D_ + d);
    }
    *(float4*)(out + ((long)b * N_ + n) * D_ + d) = v;
}

// ------------------------------------------------------------------- cond

__global__ void cond_k(const float* __restrict__ adj, unsigned char* __restrict__ cond)
{
    __shared__ float T1[64][65];
    __shared__ float T2[64][65];
    const int b = blockIdx.z;
    const int n0 = blockIdx.x * 64, m0 = blockIdx.y * 64;
    const int jj = threadIdx.x & 63, i0 = threadIdx.x >> 6;
    for (int r = 0; r < 16; ++r) {
        const int i = i0 * 16 + r;
        const int n = n0 + i, m = m0 + jj;
        T1[i][jj] = (n < N_ && m < N_) ? adj[((long)b * N_ + n) * N_ + m] : 0.f;
        const int n2 = m0 + i, m2 = n0 + jj;
        T2[i][jj] = (n2 < N_ && m2 < N_) ? adj[((long)b * N_ + n2) * N_ + m2] : 0.f;
    }
    __syncthreads();
    for (int r = 0; r < 16; ++r) {
        const int i = i0 * 16 + r;
        const int n = n0 + i, m = m0 + jj;
        if (n < N_ && m < N_) {
            const float v = T1[i][jj] + T2[jj][i] + ((n == m) ? 1.f : 0.f);
            cond[((long)b * N_ + n) * N_ + m] = (v > 0.f) ? 1 : 0;
        }
    }
}

// ------------------------------------------------------- generic fp32 GEMM
// C[m][n] = sum_k A[m][k] * (BT ? B[n][k] : B[k][n]) ; batched over blockIdx.z

template<bool BT, bool OBF>
__global__ __launch_bounds__(256) void gemm_k(
    const float* __restrict__ A, long sA, int lda,
    const float* __restrict__ B, long sB, int ldb,
    void* __restrict__ C, long sC, int ldc,
    int M, int N, int K)
{
    __shared__ alignas(16) float As[16][64];
    __shared__ alignas(16) float Bs[16][64];
    const int z = blockIdx.z;
    const float* Ab = A + (long)z * sA;
    const float* Bb = B + (long)z * sB;
    const int m0 = blockIdx.x * 64, n0 = blockIdx.y * 64;
    const int tid = threadIdx.x;
    const int tx = tid & 15, ty = tid >> 4;
    const int amm = tid >> 2, ak4 = (tid & 3) * 4;
    float acc[4][4] = {};

    for (int k0 = 0; k0 < K; k0 += 16) {
        // stage A (rows m, contiguous k)
        {
            float4 v = {0.f, 0.f, 0.f, 0.f};
            const int row = m0 + amm;
            if (row < M) {
                if (k0 + ak4 + 3 < K) {
                    v = *(const float4*)(Ab + (long)row * lda + k0 + ak4);
                } else {
                    float* vp = (float*)&v;
                    for (int j = 0; j < 4; ++j)
                        if (k0 + ak4 + j < K) vp[j] = Ab[(long)row * lda + k0 + ak4 + j];
                }
            }
            As[ak4 + 0][amm] = v.x; As[ak4 + 1][amm] = v.y;
            As[ak4 + 2][amm] = v.z; As[ak4 + 3][amm] = v.w;
        }
        // stage B
        if (BT) {
            float4 v = {0.f, 0.f, 0.f, 0.f};
            const int row = n0 + amm;
            if (row < N) {
                if (k0 + ak4 + 3 < K) {
                    v = *(const float4*)(Bb + (long)row * ldb + k0 + ak4);
                } else {
                    float* vp = (float*)&v;
                    for (int j = 0; j < 4; ++j)
                        if (k0 + ak4 + j < K) vp[j] = Bb[(long)row * ldb + k0 + ak4 + j];
                }
            }
            Bs[ak4 + 0][amm] = v.x; Bs[ak4 + 1][amm] = v.y;
            Bs[ak4 + 2][amm] = v.z; Bs[ak4 + 3][amm] = v.w;
        } else {
            const int nn = tid & 63, kb = tid >> 6;
            #pragma unroll
            for (int r = 0; r < 4; ++r) {
                const int kk = kb * 4 + r;
                float v = 0.f;
                if (k0 + kk < K && n0 + nn < N) v = Bb[(long)(k0 + kk) * ldb + n0 + nn];
                Bs[kk][nn] = v;
            }
        }
        __syncthreads();
        #pragma unroll
        for (int kk = 0; kk < 16; ++kk) {
            const float4 av = *(const float4*)&As[kk][ty * 4];
            const float4 bv = *(const float4*)&Bs[kk][tx * 4];
            const float* ap = (const float*)&av;
            const float* bp = (const float*)&bv;
            #pragma unroll
            for (int i = 0; i < 4; ++i)
                #pragma unroll
                for (int j = 0; j < 4; ++j)
                    acc[i][j] = fmaf(ap[i], bp[j], acc[i][j]);
        }
        __syncthreads();
    }
    for (int i = 0; i < 4; ++i) {
        const int m = m0 + ty * 4 + i;
        if (m >= M) break;
        for (int j = 0; j < 4; ++j) {
            const int nn = n0 + tx * 4 + j;
            if (nn < N) {
                const long idx = (long)z * sC + (long)m * ldc + nn;
                if (OBF) ((bf16*)C)[idx] = __float2bfloat16(acc[i][j]);
                else     ((float*)C)[idx] = acc[i][j];
            }
        }
    }
}

// ------------------------------------------------- softmaxes for GAT layer

__global__ void bsoft_k(const float* __restrict__ sc, float* __restrict__ mx, float* __restrict__ sm)
{
    const int idx = blockIdx.x * 256 + threadIdx.x;
    if (idx >= SCSZ) return;
    float m = -1e30f;
    for (int b = 0; b < B_; ++b) m = fmaxf(m, sc[(long)b * SCSZ + idx]);
    float s = 0.f;
    for (int b = 0; b < B_; ++b) s += expf(sc[(long)b * SCSZ + idx] - m);
    mx[idx] = m; sm[idx] = s;
}

__global__ void colsoft_k(float* __restrict__ sc, const float* __restrict__ mx,
                          const float* __restrict__ sm, const unsigned char* __restrict__ cond)
{
    const int m = blockIdx.x * 256 + threadIdx.x;
    const int b = blockIdx.y;
    if (m >= N_) return;
    float* scb = sc + (long)b * SCSZ;
    const unsigned char* cb = cond + (long)b * (N_ * N_);
    float vmax = -1e30f;
    for (int n = 0; n < N_; ++n) {
        const int o = n * SCLD + m;
        if (cb[n * N_ + m]) {
            const float e = expf(scb[o] - mx[o]) / sm[o];
            vmax = fmaxf(vmax, e);
        }
    }
    float ssum = 0.f;
    for (int n = 0; n < N_; ++n) {
        const int o = n * SCLD + m;
        if (cb[n * N_ + m]) ssum += expf(expf(scb[o] - mx[o]) / sm[o] - vmax);
    }
    const float inv = 1.0f / ssum;
    for (int n = 0; n < N_; ++n) {
        const int o = n * SCLD + m;
        float v = 0.f;
        if (cb[n * N_ + m]) v = expf(expf(scb[o] - mx[o]) / sm[o] - vmax) * inv;
        scb[o] = v;
    }
}

__global__ void nsoft_k(const float* __restrict__ hp, float* __restrict__ out)
{
    const int f = blockIdx.x * 256 + threadIdx.x;  // 0..511
    const int b = blockIdx.y;
    const float* hb = hp + (long)b * (N_ * 512) + f;
    float vmax = -1e30f;
    for (int n = 0; n < N_; ++n) vmax = fmaxf(vmax, hb[n * 512]);
    float s = 0.f;
    for (int n = 0; n < N_; ++n) s += expf(hb[n * 512] - vmax);
    const float inv = 1.0f / s;
    float* ob = out + (long)b * (N_ * 512) + f;
    for (int n = 0; n < N_; ++n) ob[n * 512] = expf(hb[n * 512] - vmax) * inv;
}

// ----------------------------------------------------------------- GRU prep

__global__ void xrev_k(const float* __restrict__ out2, const int* __restrict__ seq_lens,
                       float* __restrict__ xr)
{
    const int t = blockIdx.x, b = blockIdx.y;
    const int d = threadIdx.x * 4;
    int src = seq_lens[b] - 1 - t;
    if (src < 0) src = 0;
    *(float4*)(xr + ((long)t * B_ + b) * 512 + d) =
        *(const float4*)(out2 + ((long)b * N_ + src) * 512 + d);
}

__global__ void zero_k(float* __restrict__ p, long n)
{
    for (long i = (long)blockIdx.x * 256 + threadIdx.x; i < n; i += (long)gridDim.x * 256)
        p[i] = 0.f;
}

// ------------------------------------------------------ GRU recurrence
// Fence-free design: h state is exchanged through the die-level coherent
// point via RELAXED AGENT-scope atomic loads/stores (sc0 sc1 — bypass the
// non-coherent per-XCD L2s). No __threadfence => no buffer_wbl2/buffer_inv
// per barrier (that cache maintenance was 50 us/step in round 3). Weights
// and gi are read-only so they stay hot in L2/sL1 across all 300 steps.
// __syncthreads() before barrier arrival drains vmcnt(0) (m97 asm), so each
// block's h stores are at the coherent point before its counter increment;
// L3's total order on the counters then makes h visible to all readers.
//
// 128 blocks x 512 threads: block = (dir, 8 hidden units) x 64 batches.
// u = wave id (readfirstlane) => weight row pointers are wave-uniform s_loads.

__device__ __forceinline__ void gbar(unsigned* __restrict__ bar, int step, int grp) {
    __syncthreads();   // exec barrier + vmcnt(0) drain of this block's h stores
    if (threadIdx.x == 0) {
        const unsigned old =
            __hip_atomic_fetch_add(&bar[grp * 16], 1u, __ATOMIC_RELAXED, __HIP_MEMORY_SCOPE_AGENT);
        if (old == (unsigned)(step * 16 + 15))
            __hip_atomic_fetch_add(&bar[128], 1u, __ATOMIC_RELAXED, __HIP_MEMORY_SCOPE_AGENT);
        while (__hip_atomic_load(&bar[128], __ATOMIC_RELAXED, __HIP_MEMORY_SCOPE_AGENT)
               < (unsigned)((step + 1) * 8)) {
            __builtin_amdgcn_s_sleep(1);
        }
    }
    __syncthreads();
}

__global__ __launch_bounds__(512) void gru_recur(
    const bf16* __restrict__ gif, const bf16* __restrict__ gib,
    const float* __restrict__ Whh, const float* __restrict__ bih,
    const float* __restrict__ bhh, const int* __restrict__ seq_lens,
    float* __restrict__ hbuf, unsigned* __restrict__ bar,
    float* __restrict__ outf, float* __restrict__ outb)
{
    __shared__ alignas(16) float hs[256 * 64];  // 64 KB: half of h for 64 batches
    const int tid = threadIdx.x;
    const int b = tid & 63;
    const int w = __builtin_amdgcn_readfirstlane(tid >> 6);  // wave id 0..7
    const int dir = blockIdx.x >> 6;
    const int u = (blockIdx.x & 63) * 8 + w;
    const int grp = blockIdx.x >> 4;   // 8 groups of 16 blocks

    const float* W = Whh + (long)dir * (1536 * 512) + (long)u * 512;
    const bf16* gi = dir ? gib : gif;
    const float cr = bih[dir * 1536 + u];
    const float cz = bih[dir * 1536 + 512 + u];
    const float cn = bih[dir * 1536 + 1024 + u];
    const float br = bhh[dir * 1536 + u];
    const float bz = bhh[dir * 1536 + 512 + u];
    const float bn = bhh[dir * 1536 + 1024 + u];
    const int sl = seq_lens[b];

    // zero phase-0 h slice (via coherent point)
    __hip_atomic_store(&hbuf[dir * 32768 + u * 64 + b], 0.0f,
                       __ATOMIC_RELAXED, __HIP_MEMORY_SCOPE_AGENT);
    gbar(bar, 0, grp);

    for (int t = 0; t < N_; ++t) {
        const float* hc = hbuf + ((t & 1) ? 65536 : 0) + dir * 32768;
        float* hn       = hbuf + ((t & 1) ? 0 : 65536) + dir * 32768;
        float ar = 0.f, az = 0.f, an = 0.f, hprev = 0.f;
        for (int half = 0; half < 2; ++half) {
            __syncthreads();
            const unsigned long long* src = (const unsigned long long*)(hc + half * 16384);
            unsigned long long* dst = (unsigned long long*)hs;
            #pragma unroll
            for (int i = 0; i < 16; ++i) {
                dst[tid + 512 * i] =
                    __hip_atomic_load(&src[tid + 512 * i], __ATOMIC_RELAXED, __HIP_MEMORY_SCOPE_AGENT);
            }
            __syncthreads();
            const float* wr = W + half * 256;
            const float* wz = wr + 262144;
            const float* wn = wr + 524288;
            #pragma unroll 8
            for (int k = 0; k < 256; ++k) {
                const float hk = hs[k * 64 + b];
                ar = fmaf(hk, wr[k], ar);
                az = fmaf(hk, wz[k], az);
                an = fmaf(hk, wn[k], an);
            }
            if ((u >> 8) == half) hprev = hs[(u & 255) * 64 + b];
        }
        const long gbase = (long)t * 98304 + (long)u * 64 + b;
        const float gr = cr + __bfloat162float(gi[gbase]);
        const float gz = cz + __bfloat162float(gi[gbase + 32768]);
        const float gn = cn + __bfloat162float(gi[gbase + 65536]);
        const float r  = sigmoidf_(gr + br + ar);
        const float zg = sigmoidf_(gz + bz + az);
        const float nn = tanhf(gn + r * (bn + an));
        const float hnew = (1.f - zg) * nn + zg * hprev;
        const bool msk = t < sl;
        __hip_atomic_store(&hn[u * 64 + b], msk ? hnew : hprev,
                           __ATOMIC_RELAXED, __HIP_MEMORY_SCOPE_AGENT);
        if (dir == 0) {
            outf[(long)t * 32768 + b * 512 + u] = msk ? hnew : 0.f;   // plain store
        } else if (msk) {
            outb[(long)(sl - 1 - t) * 32768 + b * 512 + u] = hnew;    // plain store
        }
        gbar(bar, t + 1, grp);
    }
}

// --------------------------------------------------------------- finalize

__global__ void final_k(const float* __restrict__ outf, const float* __restrict__ outb,
                        const float* __restrict__ hbuf, const int* __restrict__ seq_lens,
                        float* __restrict__ dout)
{
    const long i = (long)blockIdx.x * 256 + threadIdx.x;
    const long NOUT = (long)N_ * B_ * 512;  // 9,830,400
    if (i < NOUT) {
        const int t = (int)(i >> 15);
        const int b = (int)((i >> 9) & 63);
        dout[i] = (t < seq_lens[b]) ? outf[i] + outb[i] : 0.f;
    } else if (i < NOUT + 2 * B_ * 512) {
        const long j = i - NOUT;
        const int dir = (int)(j >> 15);
        const int b = (int)((j >> 9) & 63);
        const int u = (int)(j & 511);
        dout[i] = hbuf[dir * 32768 + u * 64 + b];  // phase 0 holds final h
    }
}

__global__ void fail_zero_k(float* __restrict__ dout, long n)
{
    for (long i = (long)blockIdx.x * 256 + threadIdx.x; i < n; i += (long)gridDim.x * 256)
        dout[i] = 0.f;
}

// ----------------------------------------------------------------- launch

extern "C" void kernel_launch(void* const* d_in, const int* in_sizes, int n_in,
                              void* d_out, int out_size, void* d_ws, size_t ws_size,
                              hipStream_t stream)
{
    const int*   tokens   = (const int*)d_in[0];
    const int*   tok_lens = (const int*)d_in[1];
    const int*   seq_lens = (const int*)d_in[2];
    const float* adj      = (const float*)d_in[3];
    const float* emb      = (const float*)d_in[4];
    const float* Wq       = (const float*)d_in[5];
    const float* Wk       = (const float*)d_in[6];
    const float* Wq_o     = (const float*)d_in[7];
    const float* Wk_o     = (const float*)d_in[8];
    const float* gWih     = (const float*)d_in[9];
    const float* gWhh     = (const float*)d_in[10];
    const float* gbih     = (const float*)d_in[11];
    const float* gbhh     = (const float*)d_in[12];
    float* out = (float*)d_out;

    const long SZ = (long)B_ * N_ * 512;  // 9,830,400 floats
    float* bufA = (float*)d_ws;            // embedded -> q2 -> outf
    float* bufB = bufA + SZ;               // q1 -> k2 -> outb
    float* bufC = bufB + SZ;               // k1 -> out2
    float* bufD = bufC + SZ;               // x1 -> x_rev
    float* bufE = bufD + SZ;               // hp (both layers)
    float* sc   = bufE + SZ;               // (B, N, SCLD) scores/att
    float* mx   = sc + (long)B_ * SCSZ;
    float* smv  = mx + SCSZ;
    unsigned char* cond = (unsigned char*)(smv + SCSZ);          // B*N*N bytes (dense)
    bf16* gif = (bf16*)(cond + (long)B_ * N_ * N_);              // (300,1536,64) bf16
    bf16* gib = gif + (long)N_ * 1536 * B_;
    float* hbuf = (float*)(gib + (long)N_ * 1536 * B_);          // 2 phases x 2 dirs x 512 x 64
    unsigned* bar = (unsigned*)(hbuf + 131072);                  // 8 group counters + root
    const size_t needed = (size_t)((char*)(bar + 256) - (char*)d_ws);
    if (ws_size < needed) {  // fail visibly, not via OOB
        fail_zero_k<<<4096, 256, 0, stream>>>(out, out_size);
        return;
    }

    // 1. embedding + cond mask
    embed_k<<<dim3(N_, B_), 128, 0, stream>>>(tokens, tok_lens, seq_lens, emb, bufA);
    cond_k<<<dim3(5, 5, B_), 256, 0, stream>>>(adj, cond);

    // 2. layer-1 projections (batched over 8 heads): q1 -> bufB, k1 -> bufC
    gemm_k<false, false><<<dim3(300, 1, 8), 256, 0, stream>>>(
        bufA, 0, 512, Wq, 32768, 64, bufB, 64, 512, B_ * N_, 64, 512);
    gemm_k<false, false><<<dim3(300, 1, 8), 256, 0, stream>>>(
        bufA, 0, 512, Wk, 32768, 64, bufC, 64, 512, B_ * N_, 64, 512);

    // 3. per-head attention
    for (int h = 0; h < NHEADS_; ++h) {
        gemm_k<true, false><<<dim3(5, 5, B_), 256, 0, stream>>>(         // scores = q k^T
            bufB + h * 64, (long)N_ * 512, 512,
            bufC + h * 64, (long)N_ * 512, 512,
            sc, SCSZ, SCLD, N_, N_, 64);
        bsoft_k<<<(SCSZ + 255) / 256, 256, 0, stream>>>(sc, mx, smv);
        colsoft_k<<<dim3(2, B_), 256, 0, stream>>>(sc, mx, smv, cond);
        gemm_k<false, false><<<dim3(5, 1, B_), 256, 0, stream>>>(        // hp = att2 @ k
            sc, SCSZ, SCLD,
            bufC + h * 64, (long)N_ * 512, 512,
            bufE + h * 64, (long)N_ * 512, 512, N_, 64, N_);
    }
    nsoft_k<<<dim3(2, B_), 256, 0, stream>>>(bufE, bufD);                // x1 -> bufD

    // 4. layer-2: q2 -> bufA, k2 -> bufB
    gemm_k<false, false><<<dim3(300, 8, 1), 256, 0, stream>>>(
        bufD, 0, 512, Wq_o, 0, 512, bufA, 0, 512, B_ * N_, 512, 512);
    gemm_k<false, false><<<dim3(300, 8, 1), 256, 0, stream>>>(
        bufD, 0, 512, Wk_o, 0, 512, bufB, 0, 512, B_ * N_, 512, 512);
    gemm_k<true, false><<<dim3(5, 5, B_), 256, 0, stream>>>(
        bufA, (long)N_ * 512, 512, bufB, (long)N_ * 512, 512,
        sc, SCSZ, SCLD, N_, N_, 512);
    bsoft_k<<<(SCSZ + 255) / 256, 256, 0, stream>>>(sc, mx, smv);
    colsoft_k<<<dim3(2, B_), 256, 0, stream>>>(sc, mx, smv, cond);
    gemm_k<false, false><<<dim3(5, 8, B_), 256, 0, stream>>>(            // hp2 = att2 @ k2
        sc, SCSZ, SCLD, bufB, (long)N_ * 512, 512,
        bufE, (long)N_ * 512, 512, N_, 512, N_);
    nsoft_k<<<dim3(2, B_), 256, 0, stream>>>(bufE, bufC);                // out2 -> bufC (elu = id)

    // 5. GRU input GEMMs (bf16 out, layout (t, j, b))
    xrev_k<<<dim3(N_, B_), 128, 0, stream>>>(bufC, seq_lens, bufD);
    zero_k<<<1, 256, 0, stream>>>((float*)bar, 256);
    gemm_k<true, true><<<dim3(24, 1, N_), 256, 0, stream>>>(             // gi_f
        gWih, 0, 512, bufC, 512, (long)N_ * 512, gif, 1536 * 64, 64, 1536, 64, 512);
    gemm_k<true, true><<<dim3(24, 1, N_), 256, 0, stream>>>(             // gi_b
        gWih + 1536 * 512, 0, 512, bufD, (long)B_ * 512, 512, gib, 1536 * 64, 64, 1536, 64, 512);

    // 6. recurrence (persistent, fence-free grid sync) + finalize
    gru_recur<<<128, 512, 0, stream>>>(gif, gib, gWhh, gbih, gbhh, seq_lens,
                                       hbuf, bar, bufA, bufB);
    final_k<<<38656, 256, 0, stream>>>(bufA, bufB, hbuf, seq_lens, out);
}

// Round 5
// 12999.448 us; speedup vs baseline: 1.8117x; 1.1539x over previous
//
#include <hip/hip_runtime.h>
#include <hip/hip_bf16.h>

typedef __hip_bfloat16 bf16;
typedef unsigned long long ull;

#define B_      64
#define NMAX_   299
#define N_      300
#define D_      512
#define H_      512
#define NHEADS_ 8
#define NHID_   64
#define SCLD    304                  // padded leading dim for (n,m) score rows
#define SCSZ    (N_ * SCLD)          // 91,200 floats per batch

// ---------------------------------------------------------------- utilities

__device__ __forceinline__ float sigmoidf_(float x) { return 1.0f / (1.0f + expf(-x)); }

// ---------------------------------------------------------------- embedding

__global__ void embed_k(const int* __restrict__ tokens, const int* __restrict__ tok_lens,
                        const int* __restrict__ seq_lens, const float* __restrict__ emb,
                        float* __restrict__ out)
{
    const int n = blockIdx.x, b = blockIdx.y;
    const int d = threadIdx.x * 4;
    const int nc = seq_lens[b] - 1;
    float4 v;
    if (n < nc) {
        const int tl = tok_lens[b * NMAX_ + n];
        const int* tp = tokens + (b * NMAX_ + n) * 8;
        float4 acc = {0.f, 0.f, 0.f, 0.f};
        for (int t = 0; t < 8; ++t) {
            if (t < tl) {
                const float4 e = *(const float4*)(emb + (long)tp[t] * D_ + d);
                acc.x += e.x; acc.y += e.y; acc.z += e.z; acc.w += e.w;
            }
        }
        const float inv = 1.0f / (float)nc;
        v.x = acc.x * inv; v.y = acc.y * inv; v.z = acc.z * inv; v.w = acc.w * inv;
    } else {
        const int row = (n == nc) ? 2 : 0;
        v = *(const float4*)(emb + row * D_ + d);
    }
    *(float4*)(out + ((long)b * N_ + n) * D_ + d) = v;
}

// ------------------------------------------------------------------- cond

__global__ void cond_k(const float* __restrict__ adj, unsigned char* __restrict__ cond)
{
    __shared__ float T1[64][65];
    __shared__ float T2[64][65];
    const int b = blockIdx.z;
    const int n0 = blockIdx.x * 64, m0 = blockIdx.y * 64;
    const int jj = threadIdx.x & 63, i0 = threadIdx.x >> 6;
    for (int r = 0; r < 16; ++r) {
        const int i = i0 * 16 + r;
        const int n = n0 + i, m = m0 + jj;
        T1[i][jj] = (n < N_ && m < N_) ? adj[((long)b * N_ + n) * N_ + m] : 0.f;
        const int n2 = m0 + i, m2 = n0 + jj;
        T2[i][jj] = (n2 < N_ && m2 < N_) ? adj[((long)b * N_ + n2) * N_ + m2] : 0.f;
    }
    __syncthreads();
    for (int r = 0; r < 16; ++r) {
        const int i = i0 * 16 + r;
        const int n = n0 + i, m = m0 + jj;
        if (n < N_ && m < N_) {
            const float v = T1[i][jj] + T2[jj][i] + ((n == m) ? 1.f : 0.f);
            cond[((long)b * N_ + n) * N_ + m] = (v > 0.f) ? 1 : 0;
        }
    }
}

// ------------------------------------------------------- generic fp32 GEMM

template<bool BT, bool OBF>
__global__ __launch_bounds__(256) void gemm_k(
    const float* __restrict__ A, long sA, int lda,
    const float* __restrict__ B, long sB, int ldb,
    void* __restrict__ C, long sC, int ldc,
    int M, int N, int K)
{
    __shared__ alignas(16) float As[16][64];
    __shared__ alignas(16) float Bs[16][64];
    const int z = blockIdx.z;
    const float* Ab = A + (long)z * sA;
    const float* Bb = B + (long)z * sB;
    const int m0 = blockIdx.x * 64, n0 = blockIdx.y * 64;
    const int tid = threadIdx.x;
    const int tx = tid & 15, ty = tid >> 4;
    const int amm = tid >> 2, ak4 = (tid & 3) * 4;
    float acc[4][4] = {};

    for (int k0 = 0; k0 < K; k0 += 16) {
        {
            float4 v = {0.f, 0.f, 0.f, 0.f};
            const int row = m0 + amm;
            if (row < M) {
                if (k0 + ak4 + 3 < K) {
                    v = *(const float4*)(Ab + (long)row * lda + k0 + ak4);
                } else {
                    float* vp = (float*)&v;
                    for (int j = 0; j < 4; ++j)
                        if (k0 + ak4 + j < K) vp[j] = Ab[(long)row * lda + k0 + ak4 + j];
                }
            }
            As[ak4 + 0][amm] = v.x; As[ak4 + 1][amm] = v.y;
            As[ak4 + 2][amm] = v.z; As[ak4 + 3][amm] = v.w;
        }
        if (BT) {
            float4 v = {0.f, 0.f, 0.f, 0.f};
            const int row = n0 + amm;
            if (row < N) {
                if (k0 + ak4 + 3 < K) {
                    v = *(const float4*)(Bb + (long)row * ldb + k0 + ak4);
                } else {
                    float* vp = (float*)&v;
                    for (int j = 0; j < 4; ++j)
                        if (k0 + ak4 + j < K) vp[j] = Bb[(long)row * ldb + k0 + ak4 + j];
                }
            }
            Bs[ak4 + 0][amm] = v.x; Bs[ak4 + 1][amm] = v.y;
            Bs[ak4 + 2][amm] = v.z; Bs[ak4 + 3][amm] = v.w;
        } else {
            const int nn = tid & 63, kb = tid >> 6;
            #pragma unroll
            for (int r = 0; r < 4; ++r) {
                const int kk = kb * 4 + r;
                float v = 0.f;
                if (k0 + kk < K && n0 + nn < N) v = Bb[(long)(k0 + kk) * ldb + n0 + nn];
                Bs[kk][nn] = v;
            }
        }
        __syncthreads();
        #pragma unroll
        for (int kk = 0; kk < 16; ++kk) {
            const float4 av = *(const float4*)&As[kk][ty * 4];
            const float4 bv = *(const float4*)&Bs[kk][tx * 4];
            const float* ap = (const float*)&av;
            const float* bp = (const float*)&bv;
            #pragma unroll
            for (int i = 0; i < 4; ++i)
                #pragma unroll
                for (int j = 0; j < 4; ++j)
                    acc[i][j] = fmaf(ap[i], bp[j], acc[i][j]);
        }
        __syncthreads();
    }
    for (int i = 0; i < 4; ++i) {
        const int m = m0 + ty * 4 + i;
        if (m >= M) break;
        for (int j = 0; j < 4; ++j) {
            const int nn = n0 + tx * 4 + j;
            if (nn < N) {
                const long idx = (long)z * sC + (long)m * ldc + nn;
                if (OBF) ((bf16*)C)[idx] = __float2bfloat16(acc[i][j]);
                else     ((float*)C)[idx] = acc[i][j];
            }
        }
    }
}

// ------------------------------------------------- softmaxes for GAT layer

__global__ void bsoft_k(const float* __restrict__ sc, float* __restrict__ mx, float* __restrict__ sm)
{
    const int idx = blockIdx.x * 256 + threadIdx.x;
    if (idx >= SCSZ) return;
    float m = -1e30f;
    for (int b = 0; b < B_; ++b) m = fmaxf(m, sc[(long)b * SCSZ + idx]);
    float s = 0.f;
    for (int b = 0; b < B_; ++b) s += expf(sc[(long)b * SCSZ + idx] - m);
    mx[idx] = m; sm[idx] = s;
}

// masked softmax over n; pass 1 caches e = softmax_b value in-place, so each
// element costs 3 expf total (was 5 expf + 3 div).
__global__ void colsoft_k(float* __restrict__ sc, const float* __restrict__ mx,
                          const float* __restrict__ sm, const unsigned char* __restrict__ cond)
{
    const int m = blockIdx.x * 128 + threadIdx.x;
    const int b = blockIdx.y;
    if (m >= N_) return;
    float* scb = sc + (long)b * SCSZ;
    const unsigned char* cb = cond + (long)b * (N_ * N_);
    float vmax = -1e30f;
    for (int n = 0; n < N_; ++n) {
        const int o = n * SCLD + m;
        if (cb[n * N_ + m]) {
            const float e = expf(scb[o] - mx[o]) / sm[o];
            scb[o] = e;
            vmax = fmaxf(vmax, e);
        }
    }
    float ssum = 0.f;
    for (int n = 0; n < N_; ++n) {
        const int o = n * SCLD + m;
        if (cb[n * N_ + m]) ssum += expf(scb[o] - vmax);
    }
    const float inv = 1.0f / ssum;
    for (int n = 0; n < N_; ++n) {
        const int o = n * SCLD + m;
        scb[o] = cb[n * N_ + m] ? expf(scb[o] - vmax) * inv : 0.f;
    }
}

__global__ void nsoft_k(const float* __restrict__ hp, float* __restrict__ out)
{
    const int f = blockIdx.x * 256 + threadIdx.x;  // 0..511
    const int b = blockIdx.y;
    const float* hb = hp + (long)b * (N_ * 512) + f;
    float vmax = -1e30f;
    for (int n = 0; n < N_; ++n) vmax = fmaxf(vmax, hb[n * 512]);
    float s = 0.f;
    for (int n = 0; n < N_; ++n) s += expf(hb[n * 512] - vmax);
    const float inv = 1.0f / s;
    float* ob = out + (long)b * (N_ * 512) + f;
    for (int n = 0; n < N_; ++n) ob[n * 512] = expf(hb[n * 512] - vmax) * inv;
}

// ----------------------------------------------------------------- GRU prep

__global__ void xrev_k(const float* __restrict__ out2, const int* __restrict__ seq_lens,
                       float* __restrict__ xr)
{
    const int t = blockIdx.x, b = blockIdx.y;
    const int d = threadIdx.x * 4;
    int src = seq_lens[b] - 1 - t;
    if (src < 0) src = 0;
    *(float4*)(xr + ((long)t * B_ + b) * 512 + d) =
        *(const float4*)(out2 + ((long)b * N_ + src) * 512 + d);
}

__global__ void zero_k(float* __restrict__ p, long n)
{
    for (long i = (long)blockIdx.x * 256 + threadIdx.x; i < n; i += (long)gridDim.x * 256)
        p[i] = 0.f;
}

// ------------------------------------------------------ GRU recurrence
// 128 blocks x 512 threads; block = (dir, 8 hidden units) x 64 batches.
// h exchanged through L3 with relaxed agent-scope atomics (cache-bypass, no
// fences). Per-direction 2-level barrier (64 arrivals). h staged to LDS in
// 128-k quarters, DOUBLE-BUFFERED: quarter q+1's 8 loads are issued before
// the FMA loop over quarter q and written to the other buffer after it, so
// L3 latency hides behind ~770 cyc of FMA. Loads are batched into registers
// first (all issues precede all uses -> one vmcnt drain, not 8 round trips).

__device__ __forceinline__ void dbar(unsigned* __restrict__ gc, unsigned* __restrict__ root,
                                     int step) {
    __syncthreads();   // exec barrier + vmcnt(0) drain of this block's h stores
    if (threadIdx.x == 0) {
        const unsigned old =
            __hip_atomic_fetch_add(gc, 1u, __ATOMIC_RELAXED, __HIP_MEMORY_SCOPE_AGENT);
        if (old == (unsigned)(step * 8 + 7))
            __hip_atomic_fetch_add(root, 1u, __ATOMIC_RELAXED, __HIP_MEMORY_SCOPE_AGENT);
        while (__hip_atomic_load(root, __ATOMIC_RELAXED, __HIP_MEMORY_SCOPE_AGENT)
               < (unsigned)((step + 1) * 8)) {
            __builtin_amdgcn_s_sleep(1);
        }
    }
    __syncthreads();
}

__global__ __launch_bounds__(512) void gru_recur(
    const bf16* __restrict__ gif, const bf16* __restrict__ gib,
    const float* __restrict__ Whh, const float* __restrict__ bih,
    const float* __restrict__ bhh, const int* __restrict__ seq_lens,
    float* __restrict__ hbuf, unsigned* __restrict__ bar,
    float* __restrict__ outf, float* __restrict__ outb)
{
    __shared__ alignas(16) float hs[2][8192];   // two 32-KB k-quarter buffers
    const int tid = threadIdx.x;
    const int b = tid & 63;
    const int w = __builtin_amdgcn_readfirstlane(tid >> 6);  // wave id 0..7
    const int dir = blockIdx.x >> 6;
    const int u = (blockIdx.x & 63) * 8 + w;
    const int grp = (blockIdx.x & 63) >> 3;                  // 8 groups of 8 per dir
    unsigned* gc   = bar + (dir * 8 + grp) * 32;             // 128-B spaced counters
    unsigned* root = bar + 512 + dir * 32;

    const float* W = Whh + (long)dir * (1536 * 512) + (long)u * 512;
    const bf16* gi = dir ? gib : gif;
    const float cr = bih[dir * 1536 + u];
    const float cz = bih[dir * 1536 + 512 + u];
    const float cn = bih[dir * 1536 + 1024 + u];
    const float br = bhh[dir * 1536 + u];
    const float bz = bhh[dir * 1536 + 512 + u];
    const float bn = bhh[dir * 1536 + 1024 + u];
    const int sl = seq_lens[b];

    __hip_atomic_store(&hbuf[dir * 32768 + u * 64 + b], 0.0f,
                       __ATOMIC_RELAXED, __HIP_MEMORY_SCOPE_AGENT);
    dbar(gc, root, 0);

    for (int t = 0; t < N_; ++t) {
        const float* hc = hbuf + ((t & 1) ? 65536 : 0) + dir * 32768;
        float* hn       = hbuf + ((t & 1) ? 0 : 65536) + dir * 32768;
        const ull* hc8 = (const ull*)hc;   // 4096 ull per quarter

        ull r[8];
        // preload quarter 0 (batched: 8 issues, then 8 LDS writes)
        #pragma unroll
        for (int i = 0; i < 8; ++i)
            r[i] = __hip_atomic_load(hc8 + tid + 512 * i,
                                     __ATOMIC_RELAXED, __HIP_MEMORY_SCOPE_AGENT);
        {
            ull* dst = (ull*)hs[0];
            #pragma unroll
            for (int i = 0; i < 8; ++i) dst[tid + 512 * i] = r[i];
        }

        float ar = 0.f, az = 0.f, an = 0.f, hprev = 0.f;
        for (int q = 0; q < 4; ++q) {
            __syncthreads();                       // buf[q&1] published
            if (q < 3) {                           // issue next quarter's loads now
                const ull* src = hc8 + (q + 1) * 4096;
                #pragma unroll
                for (int i = 0; i < 8; ++i)
                    r[i] = __hip_atomic_load(src + tid + 512 * i,
                                             __ATOMIC_RELAXED, __HIP_MEMORY_SCOPE_AGENT);
            }
            const float* hq = hs[q & 1];
            const float* wr = W + q * 128;
            const float* wz = wr + 262144;
            const float* wn = wr + 524288;
            #pragma unroll 8
            for (int k = 0; k < 128; ++k) {
                const float hk = hq[k * 64 + b];
                ar = fmaf(hk, wr[k], ar);
                az = fmaf(hk, wz[k], az);
                an = fmaf(hk, wn[k], an);
            }
            if (q == (u >> 7)) hprev = hq[(u & 127) * 64 + b];
            if (q < 3) {                           // drain loads, fill other buffer
                ull* dst = (ull*)hs[(q + 1) & 1];
                #pragma unroll
                for (int i = 0; i < 8; ++i) dst[tid + 512 * i] = r[i];
            }
        }
        const long gbase = (long)t * 98304 + (long)u * 64 + b;
        const float gr = cr + __bfloat162float(gi[gbase]);
        const float gz = cz + __bfloat162float(gi[gbase + 32768]);
        const float gn = cn + __bfloat162float(gi[gbase + 65536]);
        const float rg = sigmoidf_(gr + br + ar);
        const float zg = sigmoidf_(gz + bz + az);
        const float ng = tanhf(gn + rg * (bn + an));
        const float hnew = (1.f - zg) * ng + zg * hprev;
        const bool msk = t < sl;
        __hip_atomic_store(&hn[u * 64 + b], msk ? hnew : hprev,
                           __ATOMIC_RELAXED, __HIP_MEMORY_SCOPE_AGENT);
        if (dir == 0) {
            outf[(long)t * 32768 + b * 512 + u] = msk ? hnew : 0.f;
        } else if (msk) {
            outb[(long)(sl - 1 - t) * 32768 + b * 512 + u] = hnew;
        }
        dbar(gc, root, t + 1);
    }
}

// --------------------------------------------------------------- finalize

__global__ void final_k(const float* __restrict__ outf, const float* __restrict__ outb,
                        const float* __restrict__ hbuf, const int* __restrict__ seq_lens,
                        float* __restrict__ dout)
{
    const long i = (long)blockIdx.x * 256 + threadIdx.x;
    const long NOUT = (long)N_ * B_ * 512;  // 9,830,400
    if (i < NOUT) {
        const int t = (int)(i >> 15);
        const int b = (int)((i >> 9) & 63);
        dout[i] = (t < seq_lens[b]) ? outf[i] + outb[i] : 0.f;
    } else if (i < NOUT + 2 * B_ * 512) {
        const long j = i - NOUT;
        const int dir = (int)(j >> 15);
        const int b = (int)((j >> 9) & 63);
        const int u = (int)(j & 511);
        dout[i] = hbuf[dir * 32768 + u * 64 + b];  // phase 0 holds final h
    }
}

__global__ void fail_zero_k(float* __restrict__ dout, long n)
{
    for (long i = (long)blockIdx.x * 256 + threadIdx.x; i < n; i += (long)gridDim.x * 256)
        dout[i] = 0.f;
}

// ----------------------------------------------------------------- launch

extern "C" void kernel_launch(void* const* d_in, const int* in_sizes, int n_in,
                              void* d_out, int out_size, void* d_ws, size_t ws_size,
                              hipStream_t stream)
{
    const int*   tokens   = (const int*)d_in[0];
    const int*   tok_lens = (const int*)d_in[1];
    const int*   seq_lens = (const int*)d_in[2];
    const float* adj      = (const float*)d_in[3];
    const float* emb      = (const float*)d_in[4];
    const float* Wq       = (const float*)d_in[5];
    const float* Wk       = (const float*)d_in[6];
    const float* Wq_o     = (const float*)d_in[7];
    const float* Wk_o     = (const float*)d_in[8];
    const float* gWih     = (const float*)d_in[9];
    const float* gWhh     = (const float*)d_in[10];
    const float* gbih     = (const float*)d_in[11];
    const float* gbhh     = (const float*)d_in[12];
    float* out = (float*)d_out;

    const long SZ = (long)B_ * N_ * 512;  // 9,830,400 floats
    float* bufA = (float*)d_ws;            // embedded -> q2 -> outf
    float* bufB = bufA + SZ;               // q1 -> k2 -> outb
    float* bufC = bufB + SZ;               // k1 -> out2
    float* bufD = bufC + SZ;               // x1 -> x_rev
    float* bufE = bufD + SZ;               // hp (both layers)
    float* sc   = bufE + SZ;               // (B, N, SCLD) scores/att
    float* mx   = sc + (long)B_ * SCSZ;
    float* smv  = mx + SCSZ;
    unsigned char* cond = (unsigned char*)(smv + SCSZ);          // B*N*N bytes (dense)
    bf16* gif = (bf16*)(cond + (long)B_ * N_ * N_);              // (300,1536,64) bf16
    bf16* gib = gif + (long)N_ * 1536 * B_;
    float* hbuf = (float*)(gib + (long)N_ * 1536 * B_);          // 2 phases x 2 dirs x 512 x 64
    unsigned* bar = (unsigned*)(hbuf + 131072);                  // padded counter tree
    const size_t needed = (size_t)((char*)(bar + 1024) - (char*)d_ws);
    if (ws_size < needed) {  // fail visibly, not via OOB
        fail_zero_k<<<4096, 256, 0, stream>>>(out, out_size);
        return;
    }

    // 1. embedding + cond mask
    embed_k<<<dim3(N_, B_), 128, 0, stream>>>(tokens, tok_lens, seq_lens, emb, bufA);
    cond_k<<<dim3(5, 5, B_), 256, 0, stream>>>(adj, cond);

    // 2. layer-1 projections (batched over 8 heads): q1 -> bufB, k1 -> bufC
    gemm_k<false, false><<<dim3(300, 1, 8), 256, 0, stream>>>(
        bufA, 0, 512, Wq, 32768, 64, bufB, 64, 512, B_ * N_, 64, 512);
    gemm_k<false, false><<<dim3(300, 1, 8), 256, 0, stream>>>(
        bufA, 0, 512, Wk, 32768, 64, bufC, 64, 512, B_ * N_, 64, 512);

    // 3. per-head attention
    for (int h = 0; h < NHEADS_; ++h) {
        gemm_k<true, false><<<dim3(5, 5, B_), 256, 0, stream>>>(         // scores = q k^T
            bufB + h * 64, (long)N_ * 512, 512,
            bufC + h * 64, (long)N_ * 512, 512,
            sc, SCSZ, SCLD, N_, N_, 64);
        bsoft_k<<<(SCSZ + 255) / 256, 256, 0, stream>>>(sc, mx, smv);
        colsoft_k<<<dim3(3, B_), 128, 0, stream>>>(sc, mx, smv, cond);
        gemm_k<false, false><<<dim3(5, 1, B_), 256, 0, stream>>>(        // hp = att2 @ k
            sc, SCSZ, SCLD,
            bufC + h * 64, (long)N_ * 512, 512,
            bufE + h * 64, (long)N_ * 512, 512, N_, 64, N_);
    }
    nsoft_k<<<dim3(2, B_), 256, 0, stream>>>(bufE, bufD);                // x1 -> bufD

    // 4. layer-2: q2 -> bufA, k2 -> bufB
    gemm_k<false, false><<<dim3(300, 8, 1), 256, 0, stream>>>(
        bufD, 0, 512, Wq_o, 0, 512, bufA, 0, 512, B_ * N_, 512, 512);
    gemm_k<false, false><<<dim3(300, 8, 1), 256, 0, stream>>>(
        bufD, 0, 512, Wk_o, 0, 512, bufB, 0, 512, B_ * N_, 512, 512);
    gemm_k<true, false><<<dim3(5, 5, B_), 256, 0, stream>>>(
        bufA, (long)N_ * 512, 512, bufB, (long)N_ * 512, 512,
        sc, SCSZ, SCLD, N_, N_, 512);
    bsoft_k<<<(SCSZ + 255) / 256, 256, 0, stream>>>(sc, mx, smv);
    colsoft_k<<<dim3(3, B_), 128, 0, stream>>>(sc, mx, smv, cond);
    gemm_k<false, false><<<dim3(5, 8, B_), 256, 0, stream>>>(            // hp2 = att2 @ k2
        sc, SCSZ, SCLD, bufB, (long)N_ * 512, 512,
        bufE, (long)N_ * 512, 512, N_, 512, N_);
    nsoft_k<<<dim3(2, B_), 256, 0, stream>>>(bufE, bufC);                // out2 -> bufC (elu = id)

    // 5. GRU input GEMMs (bf16 out, layout (t, j, b))
    xrev_k<<<dim3(N_, B_), 128, 0, stream>>>(bufC, seq_lens, bufD);
    zero_k<<<1, 256, 0, stream>>>((float*)bar, 1024);
    gemm_k<true, true><<<dim3(24, 1, N_), 256, 0, stream>>>(             // gi_f
        gWih, 0, 512, bufC, 512, (long)N_ * 512, gif, 1536 * 64, 64, 1536, 64, 512);
    gemm_k<true, true><<<dim3(24, 1, N_), 256, 0, stream>>>(             // gi_b
        gWih + 1536 * 512, 0, 512, bufD, (long)B_ * 512, 512, gib, 1536 * 64, 64, 1536, 64, 512);

    // 6. recurrence (persistent, fence-free per-dir sync) + finalize
    gru_recur<<<128, 512, 0, stream>>>(gif, gib, gWhh, gbih, gbhh, seq_lens,
                                       hbuf, bar, bufA, bufB);
    final_k<<<38656, 256, 0, stream>>>(bufA, bufB, hbuf, seq_lens, out);
}

// Round 6
// 12201.182 us; speedup vs baseline: 1.9302x; 1.0654x over previous
//
#include <hip/hip_runtime.h>
#include <hip/hip_bf16.h>

typedef __hip_bfloat16 bf16;
typedef unsigned long long ull;

#define B_      64
#define NMAX_   299
#define N_      300
#define D_      512
#define H_      512
#define NHEADS_ 8
#define NHID_   64
#define SCLD    304                  // padded leading dim for (n,m) score rows
#define SCSZ    (N_ * SCLD)          // 91,200 floats per batch

// ---------------------------------------------------------------- utilities

__device__ __forceinline__ float sigmoidf_(float x) { return 1.0f / (1.0f + expf(-x)); }

// ---------------------------------------------------------------- embedding

__global__ void embed_k(const int* __restrict__ tokens, const int* __restrict__ tok_lens,
                        const int* __restrict__ seq_lens, const float* __restrict__ emb,
                        float* __restrict__ out)
{
    const int n = blockIdx.x, b = blockIdx.y;
    const int d = threadIdx.x * 4;
    const int nc = seq_lens[b] - 1;
    float4 v;
    if (n < nc) {
        const int tl = tok_lens[b * NMAX_ + n];
        const int* tp = tokens + (b * NMAX_ + n) * 8;
        float4 acc = {0.f, 0.f, 0.f, 0.f};
        for (int t = 0; t < 8; ++t) {
            if (t < tl) {
                const float4 e = *(const float4*)(emb + (long)tp[t] * D_ + d);
                acc.x += e.x; acc.y += e.y; acc.z += e.z; acc.w += e.w;
            }
        }
        const float inv = 1.0f / (float)nc;
        v.x = acc.x * inv; v.y = acc.y * inv; v.z = acc.z * inv; v.w = acc.w * inv;
    } else {
        const int row = (n == nc) ? 2 : 0;
        v = *(const float4*)(emb + row * D_ + d);
    }
    *(float4*)(out + ((long)b * N_ + n) * D_ + d) = v;
}

// ------------------------------------------------------------------- cond

__global__ void cond_k(const float* __restrict__ adj, unsigned char* __restrict__ cond)
{
    __shared__ float T1[64][65];
    __shared__ float T2[64][65];
    const int b = blockIdx.z;
    const int n0 = blockIdx.x * 64, m0 = blockIdx.y * 64;
    const int jj = threadIdx.x & 63, i0 = threadIdx.x >> 6;
    for (int r = 0; r < 16; ++r) {
        const int i = i0 * 16 + r;
        const int n = n0 + i, m = m0 + jj;
        T1[i][jj] = (n < N_ && m < N_) ? adj[((long)b * N_ + n) * N_ + m] : 0.f;
        const int n2 = m0 + i, m2 = n0 + jj;
        T2[i][jj] = (n2 < N_ && m2 < N_) ? adj[((long)b * N_ + n2) * N_ + m2] : 0.f;
    }
    __syncthreads();
    for (int r = 0; r < 16; ++r) {
        const int i = i0 * 16 + r;
        const int n = n0 + i, m = m0 + jj;
        if (n < N_ && m < N_) {
            const float v = T1[i][jj] + T2[jj][i] + ((n == m) ? 1.f : 0.f);
            cond[((long)b * N_ + n) * N_ + m] = (v > 0.f) ? 1 : 0;
        }
    }
}

// ------------------------------------------------------- generic fp32 GEMM

template<bool BT, bool OBF>
__global__ __launch_bounds__(256) void gemm_k(
    const float* __restrict__ A, long sA, int lda,
    const float* __restrict__ B, long sB, int ldb,
    void* __restrict__ C, long sC, int ldc,
    int M, int N, int K)
{
    __shared__ alignas(16) float As[16][64];
    __shared__ alignas(16) float Bs[16][64];
    const int z = blockIdx.z;
    const float* Ab = A + (long)z * sA;
    const float* Bb = B + (long)z * sB;
    const int m0 = blockIdx.x * 64, n0 = blockIdx.y * 64;
    const int tid = threadIdx.x;
    const int tx = tid & 15, ty = tid >> 4;
    const int amm = tid >> 2, ak4 = (tid & 3) * 4;
    float acc[4][4] = {};

    for (int k0 = 0; k0 < K; k0 += 16) {
        {
            float4 v = {0.f, 0.f, 0.f, 0.f};
            const int row = m0 + amm;
            if (row < M) {
                if (k0 + ak4 + 3 < K) {
                    v = *(const float4*)(Ab + (long)row * lda + k0 + ak4);
                } else {
                    float* vp = (float*)&v;
                    for (int j = 0; j < 4; ++j)
                        if (k0 + ak4 + j < K) vp[j] = Ab[(long)row * lda + k0 + ak4 + j];
                }
            }
            As[ak4 + 0][amm] = v.x; As[ak4 + 1][amm] = v.y;
            As[ak4 + 2][amm] = v.z; As[ak4 + 3][amm] = v.w;
        }
        if (BT) {
            float4 v = {0.f, 0.f, 0.f, 0.f};
            const int row = n0 + amm;
            if (row < N) {
                if (k0 + ak4 + 3 < K) {
                    v = *(const float4*)(Bb + (long)row * ldb + k0 + ak4);
                } else {
                    float* vp = (float*)&v;
                    for (int j = 0; j < 4; ++j)
                        if (k0 + ak4 + j < K) vp[j] = Bb[(long)row * ldb + k0 + ak4 + j];
                }
            }
            Bs[ak4 + 0][amm] = v.x; Bs[ak4 + 1][amm] = v.y;
            Bs[ak4 + 2][amm] = v.z; Bs[ak4 + 3][amm] = v.w;
        } else {
            const int nn = tid & 63, kb = tid >> 6;
            #pragma unroll
            for (int r = 0; r < 4; ++r) {
                const int kk = kb * 4 + r;
                float v = 0.f;
                if (k0 + kk < K && n0 + nn < N) v = Bb[(long)(k0 + kk) * ldb + n0 + nn];
                Bs[kk][nn] = v;
            }
        }
        __syncthreads();
        #pragma unroll
        for (int kk = 0; kk < 16; ++kk) {
            const float4 av = *(const float4*)&As[kk][ty * 4];
            const float4 bv = *(const float4*)&Bs[kk][tx * 4];
            const float* ap = (const float*)&av;
            const float* bp = (const float*)&bv;
            #pragma unroll
            for (int i = 0; i < 4; ++i)
                #pragma unroll
                for (int j = 0; j < 4; ++j)
                    acc[i][j] = fmaf(ap[i], bp[j], acc[i][j]);
        }
        __syncthreads();
    }
    for (int i = 0; i < 4; ++i) {
        const int m = m0 + ty * 4 + i;
        if (m >= M) break;
        for (int j = 0; j < 4; ++j) {
            const int nn = n0 + tx * 4 + j;
            if (nn < N) {
                const long idx = (long)z * sC + (long)m * ldc + nn;
                if (OBF) ((bf16*)C)[idx] = __float2bfloat16(acc[i][j]);
                else     ((float*)C)[idx] = acc[i][j];
            }
        }
    }
}

// ------------------------------------------------- softmaxes for GAT layer

__global__ void bsoft_k(const float* __restrict__ sc, float* __restrict__ mx, float* __restrict__ sm)
{
    const int idx = blockIdx.x * 256 + threadIdx.x;
    if (idx >= SCSZ) return;
    float m = -1e30f;
    for (int b = 0; b < B_; ++b) m = fmaxf(m, sc[(long)b * SCSZ + idx]);
    float s = 0.f;
    for (int b = 0; b < B_; ++b) s += expf(sc[(long)b * SCSZ + idx] - m);
    mx[idx] = m; sm[idx] = s;
}

__global__ void colsoft_k(float* __restrict__ sc, const float* __restrict__ mx,
                          const float* __restrict__ sm, const unsigned char* __restrict__ cond)
{
    const int m = blockIdx.x * 128 + threadIdx.x;
    const int b = blockIdx.y;
    if (m >= N_) return;
    float* scb = sc + (long)b * SCSZ;
    const unsigned char* cb = cond + (long)b * (N_ * N_);
    float vmax = -1e30f;
    for (int n = 0; n < N_; ++n) {
        const int o = n * SCLD + m;
        if (cb[n * N_ + m]) {
            const float e = expf(scb[o] - mx[o]) / sm[o];
            scb[o] = e;
            vmax = fmaxf(vmax, e);
        }
    }
    float ssum = 0.f;
    for (int n = 0; n < N_; ++n) {
        const int o = n * SCLD + m;
        if (cb[n * N_ + m]) ssum += expf(scb[o] - vmax);
    }
    const float inv = 1.0f / ssum;
    for (int n = 0; n < N_; ++n) {
        const int o = n * SCLD + m;
        scb[o] = cb[n * N_ + m] ? expf(scb[o] - vmax) * inv : 0.f;
    }
}

__global__ void nsoft_k(const float* __restrict__ hp, float* __restrict__ out)
{
    const int f = blockIdx.x * 256 + threadIdx.x;  // 0..511
    const int b = blockIdx.y;
    const float* hb = hp + (long)b * (N_ * 512) + f;
    float vmax = -1e30f;
    for (int n = 0; n < N_; ++n) vmax = fmaxf(vmax, hb[n * 512]);
    float s = 0.f;
    for (int n = 0; n < N_; ++n) s += expf(hb[n * 512] - vmax);
    const float inv = 1.0f / s;
    float* ob = out + (long)b * (N_ * 512) + f;
    for (int n = 0; n < N_; ++n) ob[n * 512] = expf(hb[n * 512] - vmax) * inv;
}

// ----------------------------------------------------------------- GRU prep

__global__ void xrev_k(const float* __restrict__ out2, const int* __restrict__ seq_lens,
                       float* __restrict__ xr)
{
    const int t = blockIdx.x, b = blockIdx.y;
    const int d = threadIdx.x * 4;
    int src = seq_lens[b] - 1 - t;
    if (src < 0) src = 0;
    *(float4*)(xr + ((long)t * B_ + b) * 512 + d) =
        *(const float4*)(out2 + ((long)b * N_ + src) * 512 + d);
}

__global__ void zero_k(float* __restrict__ p, long n)
{
    for (long i = (long)blockIdx.x * 256 + threadIdx.x; i < n; i += (long)gridDim.x * 256)
        p[i] = 0.f;
}

// ------------------------------------------------------ GRU recurrence
// 128 blocks x 512 threads; block = (dir, 8 hidden units) x 64 batches.
// h exchanged through L3 with relaxed agent-scope atomics (cache-bypass, no
// fences); per-direction 2-level barrier; h staged to LDS in double-buffered
// 128-k quarters (loads batched to registers, FMA hides L3 latency).
//
// ROUND 6 CHANGE: Whh weights (48 KB/block) are preloaded into LDS once and
// read in the inner loop as same-address broadcast ds_reads (vectorized b128
// over unrolled k). Rounds 3-5 streamed them as wave-uniform s_loads every
// step: 6 KB/wave/step from L2 through the shallow scalar queue, sharing
// lgkmcnt with the h ds_reads -> conservative waits exposed both latencies
// (VALUBusy 13% = pure FMA issue; 87% stall). Now the only global traffic
// per step is h (L3) + gi (hoisted early, HBM-latency hidden).

__device__ __forceinline__ void dbar(unsigned* __restrict__ gc, unsigned* __restrict__ root,
                                     int step) {
    __syncthreads();   // exec barrier + vmcnt drain of this block's h stores
    if (threadIdx.x == 0) {
        const unsigned old =
            __hip_atomic_fetch_add(gc, 1u, __ATOMIC_RELAXED, __HIP_MEMORY_SCOPE_AGENT);
        if (old == (unsigned)(step * 8 + 7))
            __hip_atomic_fetch_add(root, 1u, __ATOMIC_RELAXED, __HIP_MEMORY_SCOPE_AGENT);
        while (__hip_atomic_load(root, __ATOMIC_RELAXED, __HIP_MEMORY_SCOPE_AGENT)
               < (unsigned)((step + 1) * 8)) {
            __builtin_amdgcn_s_sleep(1);
        }
    }
    __syncthreads();
}

__global__ __launch_bounds__(512) void gru_recur(
    const bf16* __restrict__ gif, const bf16* __restrict__ gib,
    const float* __restrict__ Whh, const float* __restrict__ bih,
    const float* __restrict__ bhh, const int* __restrict__ seq_lens,
    float* __restrict__ hbuf, unsigned* __restrict__ bar,
    float* __restrict__ outf, float* __restrict__ outb)
{
    __shared__ alignas(16) float hs[2][8192];    // two 32-KB k-quarter buffers
    __shared__ alignas(16) float wlds[12288];    // 48 KB: 8 u x 3 gates x 512 k
    const int tid = threadIdx.x;
    const int b = tid & 63;
    const int w = __builtin_amdgcn_readfirstlane(tid >> 6);  // wave id 0..7
    const int dir = blockIdx.x >> 6;
    const int ub = (blockIdx.x & 63) * 8;
    const int u = ub + w;
    const int grp = (blockIdx.x & 63) >> 3;                  // 8 groups of 8 per dir
    unsigned* gc   = bar + (dir * 8 + grp) * 32;             // 128-B spaced counters
    unsigned* root = bar + 512 + dir * 32;

    // ---- preload this block's Whh slice into LDS (once) ----
    // row r of 24: u_local = r/3, gate = r%3 ; 128 float4 per row
    {
        const float* Wbase = Whh + (long)dir * (1536 * 512);
        #pragma unroll
        for (int it = 0; it < 6; ++it) {
            const int idx = tid + it * 512;          // 0..3071 float4 slots
            const int row = idx >> 7;                // 0..23
            const int kc  = idx & 127;               // float4 within row
            const int ul  = row / 3, g = row % 3;
            const float4 v = *(const float4*)(Wbase + (long)(g * 512 + ub + ul) * 512 + kc * 4);
            *(float4*)(wlds + ul * 1536 + g * 512 + kc * 4) = v;
        }
    }
    const float* wl = wlds + w * 1536;   // this wave's [gate][k] slab (broadcast reads)

    const bf16* gi = dir ? gib : gif;
    const float cr = bih[dir * 1536 + u];
    const float cz = bih[dir * 1536 + 512 + u];
    const float cn = bih[dir * 1536 + 1024 + u];
    const float br = bhh[dir * 1536 + u];
    const float bz = bhh[dir * 1536 + 512 + u];
    const float bn = bhh[dir * 1536 + 1024 + u];
    const int sl = seq_lens[b];

    __hip_atomic_store(&hbuf[dir * 32768 + u * 64 + b], 0.0f,
                       __ATOMIC_RELAXED, __HIP_MEMORY_SCOPE_AGENT);
    dbar(gc, root, 0);

    for (int t = 0; t < N_; ++t) {
        const float* hc = hbuf + ((t & 1) ? 65536 : 0) + dir * 32768;
        float* hn       = hbuf + ((t & 1) ? 0 : 65536) + dir * 32768;
        const ull* hc8 = (const ull*)hc;   // 4096 ull per quarter

        // hoist gi loads: values needed only at step end; hide HBM latency
        const long gbase = (long)t * 98304 + (long)u * 64 + b;
        const float gr0 = __bfloat162float(gi[gbase]);
        const float gz0 = __bfloat162float(gi[gbase + 32768]);
        const float gn0 = __bfloat162float(gi[gbase + 65536]);

        ull r[8];
        #pragma unroll
        for (int i = 0; i < 8; ++i)
            r[i] = __hip_atomic_load(hc8 + tid + 512 * i,
                                     __ATOMIC_RELAXED, __HIP_MEMORY_SCOPE_AGENT);
        {
            ull* dst = (ull*)hs[0];
            #pragma unroll
            for (int i = 0; i < 8; ++i) dst[tid + 512 * i] = r[i];
        }

        float ar = 0.f, az = 0.f, an = 0.f, hprev = 0.f;
        for (int q = 0; q < 4; ++q) {
            __syncthreads();                       // buf[q&1] published
            if (q < 3) {                           // issue next quarter's loads now
                const ull* src = hc8 + (q + 1) * 4096;
                #pragma unroll
                for (int i = 0; i < 8; ++i)
                    r[i] = __hip_atomic_load(src + tid + 512 * i,
                                             __ATOMIC_RELAXED, __HIP_MEMORY_SCOPE_AGENT);
            }
            const float* hq = hs[q & 1];
            const float* wr = wl + q * 128;        // LDS broadcast (same addr all lanes)
            const float* wz = wr + 512;
            const float* wn = wr + 1024;
            #pragma unroll 8
            for (int k = 0; k < 128; ++k) {
                const float hk = hq[k * 64 + b];
                ar = fmaf(hk, wr[k], ar);
                az = fmaf(hk, wz[k], az);
                an = fmaf(hk, wn[k], an);
            }
            if (q == (u >> 7)) hprev = hq[(u & 127) * 64 + b];
            if (q < 3) {                           // drain loads, fill other buffer
                ull* dst = (ull*)hs[(q + 1) & 1];
                #pragma unroll
                for (int i = 0; i < 8; ++i) dst[tid + 512 * i] = r[i];
            }
        }
        const float rg = sigmoidf_(cr + gr0 + br + ar);
        const float zg = sigmoidf_(cz + gz0 + bz + az);
        const float ng = tanhf(cn + gn0 + rg * (bn + an));
        const float hnew = (1.f - zg) * ng + zg * hprev;
        const bool msk = t < sl;
        __hip_atomic_store(&hn[u * 64 + b], msk ? hnew : hprev,
                           __ATOMIC_RELAXED, __HIP_MEMORY_SCOPE_AGENT);
        if (dir == 0) {
            outf[(long)t * 32768 + b * 512 + u] = msk ? hnew : 0.f;
        } else if (msk) {
            outb[(long)(sl - 1 - t) * 32768 + b * 512 + u] = hnew;
        }
        dbar(gc, root, t + 1);
    }
}

// --------------------------------------------------------------- finalize

__global__ void final_k(const float* __restrict__ outf, const float* __restrict__ outb,
                        const float* __restrict__ hbuf, const int* __restrict__ seq_lens,
                        float* __restrict__ dout)
{
    const long i = (long)blockIdx.x * 256 + threadIdx.x;
    const long NOUT = (long)N_ * B_ * 512;  // 9,830,400
    if (i < NOUT) {
        const int t = (int)(i >> 15);
        const int b = (int)((i >> 9) & 63);
        dout[i] = (t < seq_lens[b]) ? outf[i] + outb[i] : 0.f;
    } else if (i < NOUT + 2 * B_ * 512) {
        const long j = i - NOUT;
        const int dir = (int)(j >> 15);
        const int b = (int)((j >> 9) & 63);
        const int u = (int)(j & 511);
        dout[i] = hbuf[dir * 32768 + u * 64 + b];  // phase 0 holds final h
    }
}

__global__ void fail_zero_k(float* __restrict__ dout, long n)
{
    for (long i = (long)blockIdx.x * 256 + threadIdx.x; i < n; i += (long)gridDim.x * 256)
        dout[i] = 0.f;
}

// ----------------------------------------------------------------- launch

extern "C" void kernel_launch(void* const* d_in, const int* in_sizes, int n_in,
                              void* d_out, int out_size, void* d_ws, size_t ws_size,
                              hipStream_t stream)
{
    const int*   tokens   = (const int*)d_in[0];
    const int*   tok_lens = (const int*)d_in[1];
    const int*   seq_lens = (const int*)d_in[2];
    const float* adj      = (const float*)d_in[3];
    const float* emb      = (const float*)d_in[4];
    const float* Wq       = (const float*)d_in[5];
    const float* Wk       = (const float*)d_in[6];
    const float* Wq_o     = (const float*)d_in[7];
    const float* Wk_o     = (const float*)d_in[8];
    const float* gWih     = (const float*)d_in[9];
    const float* gWhh     = (const float*)d_in[10];
    const float* gbih     = (const float*)d_in[11];
    const float* gbhh     = (const float*)d_in[12];
    float* out = (float*)d_out;

    const long SZ = (long)B_ * N_ * 512;  // 9,830,400 floats
    float* bufA = (float*)d_ws;            // embedded -> q2 -> outf
    float* bufB = bufA + SZ;               // q1 -> k2 -> outb
    float* bufC = bufB + SZ;               // k1 -> out2
    float* bufD = bufC + SZ;               // x1 -> x_rev
    float* bufE = bufD + SZ;               // hp (both layers)
    float* sc   = bufE + SZ;               // (B, N, SCLD) scores/att
    float* mx   = sc + (long)B_ * SCSZ;
    float* smv  = mx + SCSZ;
    unsigned char* cond = (unsigned char*)(smv + SCSZ);          // B*N*N bytes (dense)
    bf16* gif = (bf16*)(cond + (long)B_ * N_ * N_);              // (300,1536,64) bf16
    bf16* gib = gif + (long)N_ * 1536 * B_;
    float* hbuf = (float*)(gib + (long)N_ * 1536 * B_);          // 2 phases x 2 dirs x 512 x 64
    unsigned* bar = (unsigned*)(hbuf + 131072);                  // padded counter tree
    const size_t needed = (size_t)((char*)(bar + 1024) - (char*)d_ws);
    if (ws_size < needed) {  // fail visibly, not via OOB
        fail_zero_k<<<4096, 256, 0, stream>>>(out, out_size);
        return;
    }

    // 1. embedding + cond mask
    embed_k<<<dim3(N_, B_), 128, 0, stream>>>(tokens, tok_lens, seq_lens, emb, bufA);
    cond_k<<<dim3(5, 5, B_), 256, 0, stream>>>(adj, cond);

    // 2. layer-1 projections (batched over 8 heads): q1 -> bufB, k1 -> bufC
    gemm_k<false, false><<<dim3(300, 1, 8), 256, 0, stream>>>(
        bufA, 0, 512, Wq, 32768, 64, bufB, 64, 512, B_ * N_, 64, 512);
    gemm_k<false, false><<<dim3(300, 1, 8), 256, 0, stream>>>(
        bufA, 0, 512, Wk, 32768, 64, bufC, 64, 512, B_ * N_, 64, 512);

    // 3. per-head attention
    for (int h = 0; h < NHEADS_; ++h) {
        gemm_k<true, false><<<dim3(5, 5, B_), 256, 0, stream>>>(         // scores = q k^T
            bufB + h * 64, (long)N_ * 512, 512,
            bufC + h * 64, (long)N_ * 512, 512,
            sc, SCSZ, SCLD, N_, N_, 64);
        bsoft_k<<<(SCSZ + 255) / 256, 256, 0, stream>>>(sc, mx, smv);
        colsoft_k<<<dim3(3, B_), 128, 0, stream>>>(sc, mx, smv, cond);
        gemm_k<false, false><<<dim3(5, 1, B_), 256, 0, stream>>>(        // hp = att2 @ k
            sc, SCSZ, SCLD,
            bufC + h * 64, (long)N_ * 512, 512,
            bufE + h * 64, (long)N_ * 512, 512, N_, 64, N_);
    }
    nsoft_k<<<dim3(2, B_), 256, 0, stream>>>(bufE, bufD);                // x1 -> bufD

    // 4. layer-2: q2 -> bufA, k2 -> bufB
    gemm_k<false, false><<<dim3(300, 8, 1), 256, 0, stream>>>(
        bufD, 0, 512, Wq_o, 0, 512, bufA, 0, 512, B_ * N_, 512, 512);
    gemm_k<false, false><<<dim3(300, 8, 1), 256, 0, stream>>>(
        bufD, 0, 512, Wk_o, 0, 512, bufB, 0, 512, B_ * N_, 512, 512);
    gemm_k<true, false><<<dim3(5, 5, B_), 256, 0, stream>>>(
        bufA, (long)N_ * 512, 512, bufB, (long)N_ * 512, 512,
        sc, SCSZ, SCLD, N_, N_, 512);
    bsoft_k<<<(SCSZ + 255) / 256, 256, 0, stream>>>(sc, mx, smv);
    colsoft_k<<<dim3(3, B_), 128, 0, stream>>>(sc, mx, smv, cond);
    gemm_k<false, false><<<dim3(5, 8, B_), 256, 0, stream>>>(            // hp2 = att2 @ k2
        sc, SCSZ, SCLD, bufB, (long)N_ * 512, 512,
        bufE, (long)N_ * 512, 512, N_, 512, N_);
    nsoft_k<<<dim3(2, B_), 256, 0, stream>>>(bufE, bufC);                // out2 -> bufC (elu = id)

    // 5. GRU input GEMMs (bf16 out, layout (t, j, b))
    xrev_k<<<dim3(N_, B_), 128, 0, stream>>>(bufC, seq_lens, bufD);
    zero_k<<<1, 256, 0, stream>>>((float*)bar, 1024);
    gemm_k<true, true><<<dim3(24, 1, N_), 256, 0, stream>>>(             // gi_f
        gWih, 0, 512, bufC, 512, (long)N_ * 512, gif, 1536 * 64, 64, 1536, 64, 512);
    gemm_k<true, true><<<dim3(24, 1, N_), 256, 0, stream>>>(             // gi_b
        gWih + 1536 * 512, 0, 512, bufD, (long)B_ * 512, 512, gib, 1536 * 64, 64, 1536, 64, 512);

    // 6. recurrence (persistent, fence-free per-dir sync) + finalize
    gru_recur<<<128, 512, 0, stream>>>(gif, gib, gWhh, gbih, gbhh, seq_lens,
                                       hbuf, bar, bufA, bufB);
    final_k<<<38656, 256, 0, stream>>>(bufA, bufB, hbuf, seq_lens, out);
}

// Round 7
// 10590.710 us; speedup vs baseline: 2.2238x; 1.1521x over previous
//
#include <hip/hip_runtime.h>
#include <hip/hip_bf16.h>

typedef __hip_bfloat16 bf16;
typedef unsigned long long ull;

#define B_      64
#define NMAX_   299
#define N_      300
#define D_      512
#define H_      512
#define NHEADS_ 8
#define NHID_   64
#define SCLD    304                  // padded leading dim for (n,m) score rows
#define SCSZ    (N_ * SCLD)          // 91,200 floats per batch

// ---------------------------------------------------------------- utilities

__device__ __forceinline__ float sigmoidf_(float x) { return 1.0f / (1.0f + expf(-x)); }

// ---------------------------------------------------------------- embedding

__global__ void embed_k(const int* __restrict__ tokens, const int* __restrict__ tok_lens,
                        const int* __restrict__ seq_lens, const float* __restrict__ emb,
                        float* __restrict__ out)
{
    const int n = blockIdx.x, b = blockIdx.y;
    const int d = threadIdx.x * 4;
    const int nc = seq_lens[b] - 1;
    float4 v;
    if (n < nc) {
        const int tl = tok_lens[b * NMAX_ + n];
        const int* tp = tokens + (b * NMAX_ + n) * 8;
        float4 acc = {0.f, 0.f, 0.f, 0.f};
        for (int t = 0; t < 8; ++t) {
            if (t < tl) {
                const float4 e = *(const float4*)(emb + (long)tp[t] * D_ + d);
                acc.x += e.x; acc.y += e.y; acc.z += e.z; acc.w += e.w;
            }
        }
        const float inv = 1.0f / (float)nc;
        v.x = acc.x * inv; v.y = acc.y * inv; v.z = acc.z * inv; v.w = acc.w * inv;
    } else {
        const int row = (n == nc) ? 2 : 0;
        v = *(const float4*)(emb + row * D_ + d);
    }
    *(float4*)(out + ((long)b * N_ + n) * D_ + d) = v;
}

// ------------------------------------------------------------------- cond

__global__ void cond_k(const float* __restrict__ adj, unsigned char* __restrict__ cond)
{
    __shared__ float T1[64][65];
    __shared__ float T2[64][65];
    const int b = blockIdx.z;
    const int n0 = blockIdx.x * 64, m0 = blockIdx.y * 64;
    const int jj = threadIdx.x & 63, i0 = threadIdx.x >> 6;
    for (int r = 0; r < 16; ++r) {
        const int i = i0 * 16 + r;
        const int n = n0 + i, m = m0 + jj;
        T1[i][jj] = (n < N_ && m < N_) ? adj[((long)b * N_ + n) * N_ + m] : 0.f;
        const int n2 = m0 + i, m2 = n0 + jj;
        T2[i][jj] = (n2 < N_ && m2 < N_) ? adj[((long)b * N_ + n2) * N_ + m2] : 0.f;
    }
    __syncthreads();
    for (int r = 0; r < 16; ++r) {
        const int i = i0 * 16 + r;
        const int n = n0 + i, m = m0 + jj;
        if (n < N_ && m < N_) {
            const float v = T1[i][jj] + T2[jj][i] + ((n == m) ? 1.f : 0.f);
            cond[((long)b * N_ + n) * N_ + m] = (v > 0.f) ? 1 : 0;
        }
    }
}

// ------------------------------------------------------- generic fp32 GEMM

template<bool BT, bool OBF>
__global__ __launch_bounds__(256) void gemm_k(
    const float* __restrict__ A, long sA, int lda,
    const float* __restrict__ B, long sB, int ldb,
    void* __restrict__ C, long sC, int ldc,
    int M, int N, int K)
{
    __shared__ alignas(16) float As[16][64];
    __shared__ alignas(16) float Bs[16][64];
    const int z = blockIdx.z;
    const float* Ab = A + (long)z * sA;
    const float* Bb = B + (long)z * sB;
    const int m0 = blockIdx.x * 64, n0 = blockIdx.y * 64;
    const int tid = threadIdx.x;
    const int tx = tid & 15, ty = tid >> 4;
    const int amm = tid >> 2, ak4 = (tid & 3) * 4;
    float acc[4][4] = {};

    for (int k0 = 0; k0 < K; k0 += 16) {
        {
            float4 v = {0.f, 0.f, 0.f, 0.f};
            const int row = m0 + amm;
            if (row < M) {
                if (k0 + ak4 + 3 < K) {
                    v = *(const float4*)(Ab + (long)row * lda + k0 + ak4);
                } else {
                    float* vp = (float*)&v;
                    for (int j = 0; j < 4; ++j)
                        if (k0 + ak4 + j < K) vp[j] = Ab[(long)row * lda + k0 + ak4 + j];
                }
            }
            As[ak4 + 0][amm] = v.x; As[ak4 + 1][amm] = v.y;
            As[ak4 + 2][amm] = v.z; As[ak4 + 3][amm] = v.w;
        }
        if (BT) {
            float4 v = {0.f, 0.f, 0.f, 0.f};
            const int row = n0 + amm;
            if (row < N) {
                if (k0 + ak4 + 3 < K) {
                    v = *(const float4*)(Bb + (long)row * ldb + k0 + ak4);
                } else {
                    float* vp = (float*)&v;
                    for (int j = 0; j < 4; ++j)
                        if (k0 + ak4 + j < K) vp[j] = Bb[(long)row * ldb + k0 + ak4 + j];
                }
            }
            Bs[ak4 + 0][amm] = v.x; Bs[ak4 + 1][amm] = v.y;
            Bs[ak4 + 2][amm] = v.z; Bs[ak4 + 3][amm] = v.w;
        } else {
            const int nn = tid & 63, kb = tid >> 6;
            #pragma unroll
            for (int r = 0; r < 4; ++r) {
                const int kk = kb * 4 + r;
                float v = 0.f;
                if (k0 + kk < K && n0 + nn < N) v = Bb[(long)(k0 + kk) * ldb + n0 + nn];
                Bs[kk][nn] = v;
            }
        }
        __syncthreads();
        #pragma unroll
        for (int kk = 0; kk < 16; ++kk) {
            const float4 av = *(const float4*)&As[kk][ty * 4];
            const float4 bv = *(const float4*)&Bs[kk][tx * 4];
            const float* ap = (const float*)&av;
            const float* bp = (const float*)&bv;
            #pragma unroll
            for (int i = 0; i < 4; ++i)
                #pragma unroll
                for (int j = 0; j < 4; ++j)
                    acc[i][j] = fmaf(ap[i], bp[j], acc[i][j]);
        }
        __syncthreads();
    }
    for (int i = 0; i < 4; ++i) {
        const int m = m0 + ty * 4 + i;
        if (m >= M) break;
        for (int j = 0; j < 4; ++j) {
            const int nn = n0 + tx * 4 + j;
            if (nn < N) {
                const long idx = (long)z * sC + (long)m * ldc + nn;
                if (OBF) ((bf16*)C)[idx] = __float2bfloat16(acc[i][j]);
                else     ((float*)C)[idx] = acc[i][j];
            }
        }
    }
}

// ------------------------------------------------- softmaxes for GAT layer

__global__ void bsoft_k(const float* __restrict__ sc, float* __restrict__ mx, float* __restrict__ sm)
{
    const int idx = blockIdx.x * 256 + threadIdx.x;
    if (idx >= SCSZ) return;
    float m = -1e30f;
    for (int b = 0; b < B_; ++b) m = fmaxf(m, sc[(long)b * SCSZ + idx]);
    float s = 0.f;
    for (int b = 0; b < B_; ++b) s += expf(sc[(long)b * SCSZ + idx] - m);
    mx[idx] = m; sm[idx] = s;
}

__global__ void colsoft_k(float* __restrict__ sc, const float* __restrict__ mx,
                          const float* __restrict__ sm, const unsigned char* __restrict__ cond)
{
    const int m = blockIdx.x * 128 + threadIdx.x;
    const int b = blockIdx.y;
    if (m >= N_) return;
    float* scb = sc + (long)b * SCSZ;
    const unsigned char* cb = cond + (long)b * (N_ * N_);
    float vmax = -1e30f;
    for (int n = 0; n < N_; ++n) {
        const int o = n * SCLD + m;
        if (cb[n * N_ + m]) {
            const float e = expf(scb[o] - mx[o]) / sm[o];
            scb[o] = e;
            vmax = fmaxf(vmax, e);
        }
    }
    float ssum = 0.f;
    for (int n = 0; n < N_; ++n) {
        const int o = n * SCLD + m;
        if (cb[n * N_ + m]) ssum += expf(scb[o] - vmax);
    }
    const float inv = 1.0f / ssum;
    for (int n = 0; n < N_; ++n) {
        const int o = n * SCLD + m;
        scb[o] = cb[n * N_ + m] ? expf(scb[o] - vmax) * inv : 0.f;
    }
}

__global__ void nsoft_k(const float* __restrict__ hp, float* __restrict__ out)
{
    const int f = blockIdx.x * 256 + threadIdx.x;  // 0..511
    const int b = blockIdx.y;
    const float* hb = hp + (long)b * (N_ * 512) + f;
    float vmax = -1e30f;
    for (int n = 0; n < N_; ++n) vmax = fmaxf(vmax, hb[n * 512]);
    float s = 0.f;
    for (int n = 0; n < N_; ++n) s += expf(hb[n * 512] - vmax);
    const float inv = 1.0f / s;
    float* ob = out + (long)b * (N_ * 512) + f;
    for (int n = 0; n < N_; ++n) ob[n * 512] = expf(hb[n * 512] - vmax) * inv;
}

// ----------------------------------------------------------------- GRU prep

__global__ void xrev_k(const float* __restrict__ out2, const int* __restrict__ seq_lens,
                       float* __restrict__ xr)
{
    const int t = blockIdx.x, b = blockIdx.y;
    const int d = threadIdx.x * 4;
    int src = seq_lens[b] - 1 - t;
    if (src < 0) src = 0;
    *(float4*)(xr + ((long)t * B_ + b) * 512 + d) =
        *(const float4*)(out2 + ((long)b * N_ + src) * 512 + d);
}

__global__ void zero_k(float* __restrict__ p, long n)
{
    for (long i = (long)blockIdx.x * 256 + threadIdx.x; i < n; i += (long)gridDim.x * 256)
        p[i] = 0.f;
}

// ------------------------------------------------------ GRU recurrence
// ROUND 7: 256 blocks x 512 threads -> ALL 256 CUs (round 6 used 128: half
// the chip idle, per-CU step serial). Block = (dir, 8 u's, 32 batches).
// Wave w: u = ub + w. Lane: b32 = lane&31 (batch), kh = lane>>5 (k-half).
// Each lane accumulates 64 k's per quarter; halves combined by shfl_xor(32).
// Whh slab (48 KB) LDS-resident; h staged via relaxed agent-scope atomics
// (L3 coherent point, no fences) into double-buffered 16-KB quarter bufs.
// LDS total 81 KB -> exactly 1 block/CU. Per-dir barrier: 16 leaf groups of
// 8 -> root.

__device__ __forceinline__ void dbar(unsigned* __restrict__ gc, unsigned* __restrict__ root,
                                     int step) {
    __syncthreads();   // exec barrier + vmcnt drain of this block's h stores
    if (threadIdx.x == 0) {
        const unsigned old =
            __hip_atomic_fetch_add(gc, 1u, __ATOMIC_RELAXED, __HIP_MEMORY_SCOPE_AGENT);
        if (old == (unsigned)(step * 8 + 7))
            __hip_atomic_fetch_add(root, 1u, __ATOMIC_RELAXED, __HIP_MEMORY_SCOPE_AGENT);
        while (__hip_atomic_load(root, __ATOMIC_RELAXED, __HIP_MEMORY_SCOPE_AGENT)
               < (unsigned)((step + 1) * 16)) {
            __builtin_amdgcn_s_sleep(1);
        }
    }
    __syncthreads();
}

__global__ __launch_bounds__(512, 1) void gru_recur(
    const bf16* __restrict__ gif, const bf16* __restrict__ gib,
    const float* __restrict__ Whh, const float* __restrict__ bih,
    const float* __restrict__ bhh, const int* __restrict__ seq_lens,
    float* __restrict__ hbuf, unsigned* __restrict__ bar,
    float* __restrict__ outf, float* __restrict__ outb)
{
    __shared__ alignas(16) float hs[2][4096];    // two 16-KB k-quarter bufs (128k x 32b)
    __shared__ alignas(16) float wlds[12352];    // 48 KB (+pad to force 1 block/CU)
    const int tid = threadIdx.x;
    const int b32 = tid & 31;
    const int kh  = (tid >> 5) & 1;
    const int w = __builtin_amdgcn_readfirstlane(tid >> 6);  // wave id 0..7
    const int dir = blockIdx.x >> 7;
    const int bl  = blockIdx.x & 127;
    const int ub  = (bl >> 1) * 8;       // u-group base
    const int bh  = bl & 1;              // batch half
    const int u   = ub + w;
    const int b   = bh * 32 + b32;
    const int grp = bl >> 3;             // 16 leaf groups of 8 per dir
    unsigned* gc   = bar + (dir * 16 + grp) * 32;    // 128-B spaced leaves
    unsigned* root = bar + 1024 + dir * 32;

    // ---- preload this block's Whh slice into LDS (once) ----
    {
        const float* Wbase = Whh + (long)dir * (1536 * 512);
        #pragma unroll
        for (int it = 0; it < 6; ++it) {
            const int idx = tid + it * 512;          // 0..3071 float4 slots
            const int row = idx >> 7;                // 0..23
            const int kc  = idx & 127;               // float4 within row
            const int ul  = row / 3, g = row % 3;
            const float4 v = *(const float4*)(Wbase + (long)(g * 512 + ub + ul) * 512 + kc * 4);
            *(float4*)(wlds + ul * 1536 + g * 512 + kc * 4) = v;
        }
    }
    const float* wl = wlds + w * 1536;   // this wave's [gate][k] slab

    const bf16* gi = dir ? gib : gif;
    const float cr = bih[dir * 1536 + u];
    const float cz = bih[dir * 1536 + 512 + u];
    const float cn = bih[dir * 1536 + 1024 + u];
    const float br = bhh[dir * 1536 + u];
    const float bz = bhh[dir * 1536 + 512 + u];
    const float bn = bhh[dir * 1536 + 1024 + u];
    const int sl = seq_lens[b];

    if (tid < 256)  // lanes l<32 of each wave own (u,b) state
        __hip_atomic_store(&hbuf[dir * 32768 + u * 64 + b], 0.0f,
                           __ATOMIC_RELAXED, __HIP_MEMORY_SCOPE_AGENT);
    dbar(gc, root, 0);

    for (int t = 0; t < N_; ++t) {
        const float* hc = hbuf + ((t & 1) ? 65536 : 0) + dir * 32768;
        float* hn       = hbuf + ((t & 1) ? 0 : 65536) + dir * 32768;
        const ull* hc8 = (const ull*)hc;

        // gi for this step (values consumed at step end; HBM latency hidden)
        const long gbase = (long)t * 98304 + (long)u * 64 + b;
        const float gr0 = __bfloat162float(gi[gbase]);
        const float gz0 = __bfloat162float(gi[gbase + 32768]);
        const float gn0 = __bfloat162float(gi[gbase + 65536]);

        ull r[4];
        // preload quarter 0: rows k=0..127, this block's 32-batch half
        #pragma unroll
        for (int i = 0; i < 4; ++i) {
            const int x = i * 512 + tid;             // local ull idx 0..2047
            const int k = x >> 4, j = x & 15;
            r[i] = __hip_atomic_load(hc8 + k * 32 + bh * 16 + j,
                                     __ATOMIC_RELAXED, __HIP_MEMORY_SCOPE_AGENT);
        }
        {
            ull* dst = (ull*)hs[0];
            #pragma unroll
            for (int i = 0; i < 4; ++i) dst[i * 512 + tid] = r[i];
        }

        float ar = 0.f, az = 0.f, an = 0.f, hprev = 0.f;
        for (int q = 0; q < 4; ++q) {
            __syncthreads();                       // buf[q&1] published
            if (q < 3) {                           // issue next quarter's loads
                #pragma unroll
                for (int i = 0; i < 4; ++i) {
                    const int x = i * 512 + tid;
                    const int k = (q + 1) * 128 + (x >> 4), j = x & 15;
                    r[i] = __hip_atomic_load(hc8 + k * 32 + bh * 16 + j,
                                             __ATOMIC_RELAXED, __HIP_MEMORY_SCOPE_AGENT);
                }
            }
            const float* hq = hs[q & 1];
            const float* wr = wl + q * 128 + kh * 64;   // half-wave broadcast
            const float* wz = wr + 512;
            const float* wn = wr + 1024;
            const float* hb = hq + kh * 64 * 32 + b32;
            #pragma unroll 8
            for (int kk = 0; kk < 64; ++kk) {
                const float hk = hb[kk * 32];
                ar = fmaf(hk, wr[kk], ar);
                az = fmaf(hk, wz[kk], az);
                an = fmaf(hk, wn[kk], an);
            }
            if (q == (u >> 7)) hprev = hq[(u & 127) * 32 + b32];
            if (q < 3) {                           // drain loads, fill other buffer
                ull* dst = (ull*)hs[(q + 1) & 1];
                #pragma unroll
                for (int i = 0; i < 4; ++i) dst[i * 512 + tid] = r[i];
            }
        }
        // combine the two k-halves
        ar += __shfl_xor(ar, 32);
        az += __shfl_xor(az, 32);
        an += __shfl_xor(an, 32);

        const float rg = sigmoidf_(cr + gr0 + br + ar);
        const float zg = sigmoidf_(cz + gz0 + bz + az);
        const float ng = tanhf(cn + gn0 + rg * (bn + an));
        const float hnew = (1.f - zg) * ng + zg * hprev;
        const bool msk = t < sl;
        if (kh == 0) {
            __hip_atomic_store(&hn[u * 64 + b], msk ? hnew : hprev,
                               __ATOMIC_RELAXED, __HIP_MEMORY_SCOPE_AGENT);
            if (dir == 0) {
                outf[(long)t * 32768 + u * 64 + b] = msk ? hnew : 0.f;  // (t,u,b)
            } else if (msk) {
                outb[(long)(sl - 1 - t) * 32768 + u * 64 + b] = hnew;
            }
        }
        dbar(gc, root, t + 1);
    }
}

// --------------------------------------------------------------- finalize
// outf/outb are (t,u,b); dout is (t,b,u). Strided reads stay L2-resident
// per 128-KB t-slab.

__global__ void final_k(const float* __restrict__ outf, const float* __restrict__ outb,
                        const float* __restrict__ hbuf, const int* __restrict__ seq_lens,
                        float* __restrict__ dout)
{
    const long i = (long)blockIdx.x * 256 + threadIdx.x;
    const long NOUT = (long)N_ * B_ * 512;  // 9,830,400
    if (i < NOUT) {
        const int t = (int)(i >> 15);
        const int b = (int)((i >> 9) & 63);
        const int u = (int)(i & 511);
        const long src = (long)t * 32768 + u * 64 + b;
        dout[i] = (t < seq_lens[b]) ? outf[src] + outb[src] : 0.f;
    } else if (i < NOUT + 2 * B_ * 512) {
        const long j = i - NOUT;
        const int dir = (int)(j >> 15);
        const int b = (int)((j >> 9) & 63);
        const int u = (int)(j & 511);
        dout[i] = hbuf[dir * 32768 + u * 64 + b];  // phase 0 holds final h
    }
}

__global__ void fail_zero_k(float* __restrict__ dout, long n)
{
    for (long i = (long)blockIdx.x * 256 + threadIdx.x; i < n; i += (long)gridDim.x * 256)
        dout[i] = 0.f;
}

// ----------------------------------------------------------------- launch

extern "C" void kernel_launch(void* const* d_in, const int* in_sizes, int n_in,
                              void* d_out, int out_size, void* d_ws, size_t ws_size,
                              hipStream_t stream)
{
    const int*   tokens   = (const int*)d_in[0];
    const int*   tok_lens = (const int*)d_in[1];
    const int*   seq_lens = (const int*)d_in[2];
    const float* adj      = (const float*)d_in[3];
    const float* emb      = (const float*)d_in[4];
    const float* Wq       = (const float*)d_in[5];
    const float* Wk       = (const float*)d_in[6];
    const float* Wq_o     = (const float*)d_in[7];
    const float* Wk_o     = (const float*)d_in[8];
    const float* gWih     = (const float*)d_in[9];
    const float* gWhh     = (const float*)d_in[10];
    const float* gbih     = (const float*)d_in[11];
    const float* gbhh     = (const float*)d_in[12];
    float* out = (float*)d_out;

    const long SZ = (long)B_ * N_ * 512;  // 9,830,400 floats
    float* bufA = (float*)d_ws;            // embedded -> q2 -> outf
    float* bufB = bufA + SZ;               // q1 -> k2 -> outb
    float* bufC = bufB + SZ;               // k1 -> out2
    float* bufD = bufC + SZ;               // x1 -> x_rev
    float* bufE = bufD + SZ;               // hp (both layers)
    float* sc   = bufE + SZ;               // (B, N, SCLD) scores/att
    float* mx   = sc + (long)B_ * SCSZ;
    float* smv  = mx + SCSZ;
    unsigned char* cond = (unsigned char*)(smv + SCSZ);          // B*N*N bytes (dense)
    bf16* gif = (bf16*)(cond + (long)B_ * N_ * N_);              // (300,1536,64) bf16
    bf16* gib = gif + (long)N_ * 1536 * B_;
    float* hbuf = (float*)(gib + (long)N_ * 1536 * B_);          // 2 phases x 2 dirs x 512 x 64
    unsigned* bar = (unsigned*)(hbuf + 131072);                  // padded counter tree
    const size_t needed = (size_t)((char*)(bar + 2048) - (char*)d_ws);
    if (ws_size < needed) {  // fail visibly, not via OOB
        fail_zero_k<<<4096, 256, 0, stream>>>(out, out_size);
        return;
    }

    // 1. embedding + cond mask
    embed_k<<<dim3(N_, B_), 128, 0, stream>>>(tokens, tok_lens, seq_lens, emb, bufA);
    cond_k<<<dim3(5, 5, B_), 256, 0, stream>>>(adj, cond);

    // 2. layer-1 projections (batched over 8 heads): q1 -> bufB, k1 -> bufC
    gemm_k<false, false><<<dim3(300, 1, 8), 256, 0, stream>>>(
        bufA, 0, 512, Wq, 32768, 64, bufB, 64, 512, B_ * N_, 64, 512);
    gemm_k<false, false><<<dim3(300, 1, 8), 256, 0, stream>>>(
        bufA, 0, 512, Wk, 32768, 64, bufC, 64, 512, B_ * N_, 64, 512);

    // 3. per-head attention
    for (int h = 0; h < NHEADS_; ++h) {
        gemm_k<true, false><<<dim3(5, 5, B_), 256, 0, stream>>>(         // scores = q k^T
            bufB + h * 64, (long)N_ * 512, 512,
            bufC + h * 64, (long)N_ * 512, 512,
            sc, SCSZ, SCLD, N_, N_, 64);
        bsoft_k<<<(SCSZ + 255) / 256, 256, 0, stream>>>(sc, mx, smv);
        colsoft_k<<<dim3(3, B_), 128, 0, stream>>>(sc, mx, smv, cond);
        gemm_k<false, false><<<dim3(5, 1, B_), 256, 0, stream>>>(        // hp = att2 @ k
            sc, SCSZ, SCLD,
            bufC + h * 64, (long)N_ * 512, 512,
            bufE + h * 64, (long)N_ * 512, 512, N_, 64, N_);
    }
    nsoft_k<<<dim3(2, B_), 256, 0, stream>>>(bufE, bufD);                // x1 -> bufD

    // 4. layer-2: q2 -> bufA, k2 -> bufB
    gemm_k<false, false><<<dim3(300, 8, 1), 256, 0, stream>>>(
        bufD, 0, 512, Wq_o, 0, 512, bufA, 0, 512, B_ * N_, 512, 512);
    gemm_k<false, false><<<dim3(300, 8, 1), 256, 0, stream>>>(
        bufD, 0, 512, Wk_o, 0, 512, bufB, 0, 512, B_ * N_, 512, 512);
    gemm_k<true, false><<<dim3(5, 5, B_), 256, 0, stream>>>(
        bufA, (long)N_ * 512, 512, bufB, (long)N_ * 512, 512,
        sc, SCSZ, SCLD, N_, N_, 512);
    bsoft_k<<<(SCSZ + 255) / 256, 256, 0, stream>>>(sc, mx, smv);
    colsoft_k<<<dim3(3, B_), 128, 0, stream>>>(sc, mx, smv, cond);
    gemm_k<false, false><<<dim3(5, 8, B_), 256, 0, stream>>>(            // hp2 = att2 @ k2
        sc, SCSZ, SCLD, bufB, (long)N_ * 512, 512,
        bufE, (long)N_ * 512, 512, N_, 512, N_);
    nsoft_k<<<dim3(2, B_), 256, 0, stream>>>(bufE, bufC);                // out2 -> bufC (elu = id)

    // 5. GRU input GEMMs (bf16 out, layout (t, j, b))
    xrev_k<<<dim3(N_, B_), 128, 0, stream>>>(bufC, seq_lens, bufD);
    zero_k<<<1, 256, 0, stream>>>((float*)bar, 2048);
    gemm_k<true, true><<<dim3(24, 1, N_), 256, 0, stream>>>(             // gi_f
        gWih, 0, 512, bufC, 512, (long)N_ * 512, gif, 1536 * 64, 64, 1536, 64, 512);
    gemm_k<true, true><<<dim3(24, 1, N_), 256, 0, stream>>>(             // gi_b
        gWih + 1536 * 512, 0, 512, bufD, (long)B_ * 512, 512, gib, 1536 * 64, 64, 1536, 64, 512);

    // 6. recurrence (persistent, fence-free per-dir sync, full chip) + finalize
    gru_recur<<<256, 512, 0, stream>>>(gif, gib, gWhh, gbih, gbhh, seq_lens,
                                       hbuf, bar, bufA, bufB);
    final_k<<<38656, 256, 0, stream>>>(bufA, bufB, hbuf, seq_lens, out);
}